// Round 12
// baseline (486.774 us; speedup 1.0000x reference)
//
#include <hip/hip_runtime.h>
#include <math.h>

// N=50000, E=800000, nfeat=256, hid=256, nclass=40, nstruc=128, heads=8
typedef __attribute__((ext_vector_type(8))) short short8;
typedef __attribute__((ext_vector_type(4))) ushort u16x4;
typedef __attribute__((ext_vector_type(8))) ushort u16x8;
typedef __attribute__((ext_vector_type(8))) __bf16 bf16x8;
typedef __attribute__((ext_vector_type(4))) float f32x4;

__device__ inline ushort f2bf(float x) {
  union { float f; unsigned u; } v; v.f = x;
  unsigned r = v.u + 0x7fff + ((v.u >> 16) & 1);
  return (ushort)(r >> 16);
}
__device__ inline float bf2f(ushort b) {
  union { unsigned u; float f; } v; v.u = (unsigned)b << 16; return v.f;
}

// ---------------- pack weights into MFMA fragment order (plain bf16) ----------------
// frag order: off = ((kb*(Fp/16)+nb)*64 + lane)*8 + j ; lane=(kr>>3)*16|(n&15), j=kr&7
template <int F, int Fp>
__global__ void pack_b(const float* __restrict__ B, ushort* __restrict__ Bp) {
  int tid = blockIdx.x * blockDim.x + threadIdx.x;
  if (tid >= 256 * Fp) return;
  int k = tid / Fp, n = tid % Fp;
  float val = (n < F) ? B[k * F + n] : 0.f;
  int kb = k >> 5, kr = k & 31;
  int lane = ((kr >> 3) << 4) | (n & 15);
  int j = kr & 7;
  int nb = n >> 4;
  size_t off = ((size_t)(kb * (Fp / 16) + nb) * 64 + lane) * 8 + j;
  Bp[off] = f2bf(val);
}

// W_att [8][256][32] -> logical B[k][n], n = h*32+j2
__global__ void pack_watt_frag(const float* __restrict__ W_att, ushort* __restrict__ Bp) {
  int tid = blockIdx.x * blockDim.x + threadIdx.x;
  if (tid >= 256 * 256) return;
  int k = tid >> 8, n = tid & 255;
  float val = W_att[(size_t)(n >> 5) * 8192 + k * 32 + (n & 31)];
  int kb = k >> 5, kr = k & 31;
  int lane = ((kr >> 3) << 4) | (n & 15);
  int j = kr & 7;
  int nb = n >> 4;
  size_t off = ((size_t)(kb * 16 + nb) * 64 + lane) * 8 + j;
  Bp[off] = f2bf(val);
}

// ---------------- bf16 MFMA GEMM: C[N,F] = A[N,256] @ B[256,F] (+bias) ----------------
// BM=32, 512 threads (8 waves: 2 row-groups x 4 col-groups), 16 KiB LDS.
// OUTMODE: 0 = f32 only, 1 = f32 + bf16 copy, 2 = bf16 only
template <int Fp, int F, int OUTMODE, bool BIAS, bool BFIN>
__global__ __launch_bounds__(512) void gemm_mfma(const float* __restrict__ A,
                                                 const ushort* __restrict__ Ab,
                                                 const ushort* __restrict__ Bp,
                                                 const float* __restrict__ bias,
                                                 float* __restrict__ C,
                                                 ushort* __restrict__ Cb, int N) {
  constexpr int NB = Fp / 64;
  __shared__ ushort lhs[32 * 256];
  int n0 = blockIdx.x * 32;
  int t = threadIdx.x;
  {
    int r = t >> 4, q = t & 15;
    int row = n0 + r;
    bool rin = row < N;
#pragma unroll
    for (int i = 0; i < 2; ++i) {
      int c0 = q * 16 + i * 8;
      int c8 = (c0 >> 3) ^ (r & 7);
      if (BFIN) {
        u16x8 hv = (u16x8){0, 0, 0, 0, 0, 0, 0, 0};
        if (rin) hv = *reinterpret_cast<const u16x8*>(Ab + (size_t)row * 256 + c0);
        *reinterpret_cast<u16x8*>(&lhs[r * 256 + c8 * 8]) = hv;
      } else {
        float4 f0 = {0.f, 0.f, 0.f, 0.f}, f1 = {0.f, 0.f, 0.f, 0.f};
        if (rin) {
          f0 = *reinterpret_cast<const float4*>(A + (size_t)row * 256 + c0);
          f1 = *reinterpret_cast<const float4*>(A + (size_t)row * 256 + c0 + 4);
        }
        float ff[8] = {f0.x, f0.y, f0.z, f0.w, f1.x, f1.y, f1.z, f1.w};
        short8 sh;
#pragma unroll
        for (int j = 0; j < 8; ++j) sh[j] = (short)f2bf(ff[j]);
        *reinterpret_cast<short8*>(&lhs[r * 256 + c8 * 8]) = sh;
      }
    }
  }
  __syncthreads();
  int w = t >> 6, l = t & 63;
  int wr = w >> 2, wc = w & 3;
  int lr = l & 15, lk = l >> 4;
  f32x4 acc[NB];
#pragma unroll
  for (int nb = 0; nb < NB; ++nb) acc[nb] = (f32x4){0.f, 0.f, 0.f, 0.f};

#pragma unroll
  for (int ks = 0; ks < 8; ++ks) {
    int row = wr * 16 + lr;
    int c8 = (ks * 4 + lk) ^ (row & 7);
    bf16x8 ah = *reinterpret_cast<const bf16x8*>(&lhs[row * 256 + c8 * 8]);
#pragma unroll
    for (int nb = 0; nb < NB; ++nb) {
      size_t off = ((size_t)(ks * (Fp / 16) + wc * NB + nb) * 64 + l) * 8;
      bf16x8 bh = *reinterpret_cast<const bf16x8*>(&Bp[off]);
      acc[nb] = __builtin_amdgcn_mfma_f32_16x16x32_bf16(ah, bh, acc[nb], 0, 0, 0);
    }
  }
  int rowbase = n0 + wr * 16 + lk * 4;
#pragma unroll
  for (int nb = 0; nb < NB; ++nb) {
    int col = wc * (NB * 16) + nb * 16 + lr;
    if (col < F) {
      float bi = BIAS ? bias[col] : 0.f;
#pragma unroll
      for (int rg = 0; rg < 4; ++rg) {
        if (rowbase + rg < N) {
          float v = acc[nb][rg] + bi;
          if (OUTMODE != 2) C[(size_t)(rowbase + rg) * F + col] = v;
          if (OUTMODE != 0) Cb[(size_t)(rowbase + rg) * F + col] = f2bf(v);
        }
      }
    }
  }
}

// ---------------- s1/s2 packs per node per head (bf16 H input) ----------------
// s1pack/s2pack[n*8+h] = {s, exp(-s), exp(-0.2*s), 0}
__global__ void calc_s12(const ushort* __restrict__ Hb, const float* __restrict__ a1,
                         const float* __restrict__ a2, float4* __restrict__ s1pack,
                         float4* __restrict__ s2pack, int N) {
  int tid = blockIdx.x * blockDim.x + threadIdx.x;
  if (tid >= N * 8) return;
  int h = tid & 7;
  int n = tid >> 3;
  const ushort* hp = Hb + (size_t)n * 256 + h * 32;
  const float* A1 = a1 + h * 32;
  const float* A2 = a2 + h * 32;
  float d1 = 0.f, d2 = 0.f;
#pragma unroll
  for (int j0 = 0; j0 < 32; j0 += 8) {
    u16x8 hv = *reinterpret_cast<const u16x8*>(hp + j0);
#pragma unroll
    for (int j = 0; j < 8; ++j) {
      float v = bf2f(hv[j]);
      d1 = fmaf(v, A1[j0 + j], d1);
      d2 = fmaf(v, A2[j0 + j], d2);
    }
  }
  s1pack[tid] = (float4){d1, expf(-d1), expf(-0.2f * d1), 0.f};
  s2pack[tid] = (float4){d2, expf(-d2), expf(-0.2f * d2), 0.f};
}

__global__ void calc_s12_out(const float* __restrict__ Ho, const float* __restrict__ a1o,
                             const float* __restrict__ a2o, float* __restrict__ s1o,
                             float* __restrict__ s2o, int N) {
  int n = blockIdx.x * blockDim.x + threadIdx.x;
  if (n >= N) return;
  const float* hp = Ho + (size_t)n * 40;
  float d1 = 0.f, d2 = 0.f;
#pragma unroll
  for (int j = 0; j < 40; ++j) {
    float v = hp[j];
    d1 = fmaf(v, a1o[j], d1);
    d2 = fmaf(v, a2o[j], d2);
  }
  s1o[n] = d1;
  s2o[n] = d2;
}

// ---------------- CSR build ----------------
__global__ void hist_deg(const int* __restrict__ row, int* __restrict__ deg, int E) {
  int e = blockIdx.x * blockDim.x + threadIdx.x;
  if (e < E) atomicAdd(&deg[row[e]], 1);
}

__global__ void scan1(const int* __restrict__ deg, int* __restrict__ rp, int* __restrict__ bsum,
                      int N) {
  __shared__ int sd[256];
  int t = threadIdx.x;
  int i = blockIdx.x * 256 + t;
  int v = (i < N) ? deg[i] : 0;
  sd[t] = v;
  __syncthreads();
  for (int off = 1; off < 256; off <<= 1) {
    int x = (t >= off) ? sd[t - off] : 0;
    __syncthreads();
    sd[t] += x;
    __syncthreads();
  }
  if (i < N) rp[i] = sd[t] - v;
  if (t == 255) bsum[blockIdx.x] = sd[255];
}

__global__ void scan2(int* __restrict__ bsum, int nb) {
  __shared__ int sd[256];
  int t = threadIdx.x;
  int v = (t < nb) ? bsum[t] : 0;
  sd[t] = v;
  __syncthreads();
  for (int off = 1; off < 256; off <<= 1) {
    int x = (t >= off) ? sd[t - off] : 0;
    __syncthreads();
    sd[t] += x;
    __syncthreads();
  }
  if (t < nb) bsum[t] = sd[t] - v;
}

__global__ void scan3(int* __restrict__ rp, const int* __restrict__ bsum, int N, int E) {
  int i = blockIdx.x * 256 + threadIdx.x;
  if (i < N) rp[i] += bsum[blockIdx.x];
  if (i == 0) rp[N] = E;
}

__global__ void scatter_edges(const int* __restrict__ row, const int* __restrict__ col,
                              const int* __restrict__ rp, int* __restrict__ cur,
                              int* __restrict__ scol, int* __restrict__ srow, int E) {
  int e = blockIdx.x * blockDim.x + threadIdx.x;
  if (e >= E) return;
  int r = row[e];
  int p = atomicAdd(&cur[r], 1);
  int idx = rp[r] + p;
  scol[idx] = col[e];
  srow[idx] = r;
}

// ---------------- output-head edge weights (parallel) ----------------
__global__ void edge_wo(const int* __restrict__ srow, const int* __restrict__ scol,
                        const float* __restrict__ s1o, const float* __restrict__ s2o,
                        float* __restrict__ wo, int E) {
  int e = blockIdx.x * blockDim.x + threadIdx.x;
  if (e >= E) return;
  float lg = s1o[srow[e]] + s2o[scol[e]];
  float lr = lg > 0.f ? lg : 0.2f * lg;
  wo[e] = expf(-lr);
}

// ---------------- GAT layer-1 aggregation (separable exp): one wave/node ----------------
__global__ __launch_bounds__(64) void agg_att(const ushort* __restrict__ Hb,
                                              const float4* __restrict__ s1pack,
                                              const float4* __restrict__ s2pack,
                                              const int* __restrict__ rp,
                                              const int* __restrict__ scol,
                                              ushort* __restrict__ h1b, int N) {
  int n = blockIdx.x;
  int t = threadIdx.x;          // features t*4..t*4+3 ; head = t>>3
  int head = t >> 3;
  float4 s1p = s1pack[n * 8 + head];   // {s1, e^-s1, e^-0.2s1}
  float acc[4] = {0.f, 0.f, 0.f, 0.f};
  float rs = 0.f;
  int beg = rp[n], end = rp[n + 1];
  for (int i = beg; i < end; ++i) {
    int c = scol[i];
    float4 s2p = s2pack[c * 8 + head];
    float x = s1p.x + s2p.x;
    float wv = x > 0.f ? s1p.y * s2p.y : s1p.z * s2p.z;
    rs += wv;
    const u16x4 hv = *reinterpret_cast<const u16x4*>(Hb + (size_t)c * 256 + t * 4);
#pragma unroll
    for (int j = 0; j < 4; ++j) acc[j] = fmaf(wv, bf2f(hv[j]), acc[j]);
  }
  float inv = 1.f / (rs + 1e-16f);
  u16x4 ov;
#pragma unroll
  for (int j = 0; j < 4; ++j) {
    float v = acc[j] * inv;
    v = v > 0.f ? v : expm1f(v);
    ov[j] = f2bf(v);
  }
  *reinterpret_cast<u16x4*>(h1b + (size_t)n * 256 + t * 4) = ov;
}

// ---------------- GraphConv aggregation: one wave/node ----------------
__global__ __launch_bounds__(64) void agg_gc(const ushort* __restrict__ Sb,
                                             const int* __restrict__ rp,
                                             const int* __restrict__ scol,
                                             const float* __restrict__ b_gc,
                                             ushort* __restrict__ h2b, int N) {
  int n = blockIdx.x;
  int t = threadIdx.x;
  float acc[4] = {0.f, 0.f, 0.f, 0.f};
  int beg = rp[n], end = rp[n + 1];
  for (int i = beg; i < end; ++i) {
    int c = scol[i];
    const u16x4 sv = *reinterpret_cast<const u16x4*>(Sb + (size_t)c * 256 + t * 4);
#pragma unroll
    for (int j = 0; j < 4; ++j) acc[j] += bf2f(sv[j]);
  }
  const float4 bv = *reinterpret_cast<const float4*>(b_gc + t * 4);
  float o[4] = {acc[0] + bv.x, acc[1] + bv.y, acc[2] + bv.z, acc[3] + bv.w};
  u16x4 ov;
#pragma unroll
  for (int j = 0; j < 4; ++j) ov[j] = f2bf(o[j]);
  *reinterpret_cast<u16x4*>(h2b + (size_t)n * 256 + t * 4) = ov;
}

// ---------------- output head aggregation + elu + log_softmax ----------------
__global__ __launch_bounds__(64) void agg_out_lsm(const ushort* __restrict__ Hob,
                                                  const float* __restrict__ wo,
                                                  const int* __restrict__ rp,
                                                  const int* __restrict__ scol,
                                                  float* __restrict__ out0, int N) {
  int n = blockIdx.x;
  int t = threadIdx.x;
  float acc = 0.f, rs = 0.f;
  int beg = rp[n], end = rp[n + 1];
  for (int i = beg; i < end; ++i) {
    int c = scol[i];
    float wv = wo[i];
    rs += wv;
    if (t < 40) acc = fmaf(wv, bf2f(Hob[(size_t)c * 40 + t]), acc);
  }
  float hp = acc / (rs + 1e-16f);
  float xo = (t < 40) ? (hp > 0.f ? hp : expm1f(hp)) : -3.0e38f;
  float mx = xo;
#pragma unroll
  for (int m = 1; m < 64; m <<= 1) mx = fmaxf(mx, __shfl_xor(mx, m));
  float ex = (t < 40) ? expf(xo - mx) : 0.f;
  float sum = ex;
#pragma unroll
  for (int m = 1; m < 64; m <<= 1) sum += __shfl_xor(sum, m);
  if (t < 40) out0[(size_t)n * 40 + t] = xo - mx - logf(sum);
}

// ---------------- launch ----------------
extern "C" void kernel_launch(void* const* d_in, const int* in_sizes, int n_in,
                              void* d_out, int out_size, void* d_ws, size_t ws_size,
                              hipStream_t stream) {
  const float* x      = (const float*)d_in[0];
  const int*   ei     = (const int*)d_in[1];
  const float* W_att  = (const float*)d_in[2];
  const float* a1     = (const float*)d_in[3];
  const float* a2     = (const float*)d_in[4];
  const float* W_out  = (const float*)d_in[5];
  const float* a1_out = (const float*)d_in[6];
  const float* a2_out = (const float*)d_in[7];
  const float* W_gc   = (const float*)d_in[8];
  const float* b_gc   = (const float*)d_in[9];
  const float* W_enc  = (const float*)d_in[10];
  const float* b_enc  = (const float*)d_in[11];

  const int N = in_sizes[0] / 256;
  const int E = in_sizes[1] / 2;
  const int* row = ei;
  const int* col = ei + E;

  char* p = (char*)d_ws;
  auto alloc = [&](size_t bytes) -> void* {
    void* r = (void*)p;
    p += (bytes + 255) & ~(size_t)255;
    return r;
  };
  ushort* hbuf = (ushort*)alloc((size_t)N * 256 * 2);  // bf16: H, then support
  ushort* h1b  = (ushort*)alloc((size_t)N * 256 * 2);
  ushort* h2b  = (ushort*)alloc((size_t)N * 256 * 2);
  float* Ho   = (float*)alloc((size_t)N * 40 * 4);
  ushort* Hob = (ushort*)alloc((size_t)N * 40 * 2);
  float4* s1pack = (float4*)alloc((size_t)N * 8 * 16);
  float4* s2pack = (float4*)alloc((size_t)N * 8 * 16);
  float* s1o  = (float*)alloc((size_t)N * 4);
  float* s2o  = (float*)alloc((size_t)N * 4);
  int* deg    = (int*)alloc((size_t)N * 4);
  int* rp     = (int*)alloc((size_t)(N + 1) * 4);
  int* bsum   = (int*)alloc(256 * 4);
  int* scol   = (int*)alloc((size_t)E * 4);
  int* srow   = (int*)alloc((size_t)E * 4);
  float* wo   = (float*)alloc((size_t)E * 4);
  ushort* Bp  = (ushort*)alloc((size_t)65536 * 2);
  ushort* Wg  = (ushort*)alloc((size_t)65536 * 2);
  ushort* We  = (ushort*)alloc((size_t)32768 * 2);
  ushort* Wo  = (ushort*)alloc((size_t)16384 * 2);

  float* out0 = (float*)d_out;
  float* outY = out0 + (size_t)N * 40;
  float* outZ = outY + (size_t)N * 128;

  const int nb = (N + 255) / 256;
  const int gblk = (N + 31) / 32;

  // weight packing
  pack_watt_frag<<<dim3(256), dim3(256), 0, stream>>>(W_att, Bp);
  pack_b<256, 256><<<dim3(256), dim3(256), 0, stream>>>(W_gc, Wg);
  pack_b<128, 128><<<dim3(128), dim3(256), 0, stream>>>(W_enc, We);
  pack_b<40, 64><<<dim3(64), dim3(256), 0, stream>>>(W_out, Wo);

  // CSR build (counting sort by row)
  hipMemsetAsync(deg, 0, (size_t)N * 4, stream);
  hist_deg<<<dim3((E + 255) / 256), dim3(256), 0, stream>>>(row, deg, E);
  scan1<<<dim3(nb), dim3(256), 0, stream>>>(deg, rp, bsum, N);
  scan2<<<dim3(1), dim3(256), 0, stream>>>(bsum, nb);
  scan3<<<dim3(nb), dim3(256), 0, stream>>>(rp, bsum, N, E);
  hipMemsetAsync(deg, 0, (size_t)N * 4, stream);  // reuse as cursor
  scatter_edges<<<dim3((E + 255) / 256), dim3(256), 0, stream>>>(row, col, rp, deg, scol, srow, E);

  // layer 1: H = x @ W_att(all heads), bf16 out
  gemm_mfma<256, 256, 2, false, false><<<dim3(gblk), dim3(512), 0, stream>>>(
      x, nullptr, Bp, nullptr, nullptr, hbuf, N);
  calc_s12<<<dim3((N * 8 + 255) / 256), dim3(256), 0, stream>>>(hbuf, a1, a2, s1pack, s2pack, N);
  agg_att<<<dim3(N), dim3(64), 0, stream>>>(hbuf, s1pack, s2pack, rp, scol, h1b, N);

  // GraphConv: support bf16 (overwrites hbuf)
  gemm_mfma<256, 256, 2, false, true><<<dim3(gblk), dim3(512), 0, stream>>>(
      nullptr, h1b, Wg, nullptr, nullptr, hbuf, N);
  agg_gc<<<dim3(N), dim3(64), 0, stream>>>(hbuf, rp, scol, b_gc, h2b, N);

  // output head: Ho f32 (for s12o) + bf16 copy (for gather)
  gemm_mfma<64, 40, 1, false, true><<<dim3(gblk), dim3(512), 0, stream>>>(
      nullptr, h2b, Wo, nullptr, Ho, Hob, N);
  calc_s12_out<<<dim3((N + 255) / 256), dim3(256), 0, stream>>>(Ho, a1_out, a2_out, s1o, s2o, N);
  edge_wo<<<dim3((E + 255) / 256), dim3(256), 0, stream>>>(srow, scol, s1o, s2o, wo, E);
  agg_out_lsm<<<dim3(N), dim3(64), 0, stream>>>(Hob, wo, rp, scol, out0, N);

  // y, z
  gemm_mfma<128, 128, 0, true, true><<<dim3(gblk), dim3(512), 0, stream>>>(
      nullptr, h1b, We, b_enc, outY, nullptr, N);
  gemm_mfma<128, 128, 0, true, true><<<dim3(gblk), dim3(512), 0, stream>>>(
      nullptr, h2b, We, b_enc, outZ, nullptr, N);
}

// Round 13
// 413.065 us; speedup vs baseline: 1.1784x; 1.1784x over previous
//
#include <hip/hip_runtime.h>
#include <math.h>

// N=50000, E=800000, nfeat=256, hid=256, nclass=40, nstruc=128, heads=8
typedef __attribute__((ext_vector_type(8))) short short8;
typedef __attribute__((ext_vector_type(4))) ushort u16x4;
typedef __attribute__((ext_vector_type(8))) ushort u16x8;
typedef __attribute__((ext_vector_type(8))) __bf16 bf16x8;
typedef __attribute__((ext_vector_type(4))) float f32x4;

__device__ inline ushort f2bf(float x) {
  union { float f; unsigned u; } v; v.f = x;
  unsigned r = v.u + 0x7fff + ((v.u >> 16) & 1);
  return (ushort)(r >> 16);
}
__device__ inline float bf2f(ushort b) {
  union { unsigned u; float f; } v; v.u = (unsigned)b << 16; return v.f;
}

// ---------------- pack weights into MFMA fragment order (plain bf16) ----------------
// frag order: off = ((kb*(Fp/16)+nb)*64 + lane)*8 + j ; lane=(kr>>3)*16|(n&15), j=kr&7
template <int F, int Fp>
__global__ void pack_b(const float* __restrict__ B, ushort* __restrict__ Bp) {
  int tid = blockIdx.x * blockDim.x + threadIdx.x;
  if (tid >= 256 * Fp) return;
  int k = tid / Fp, n = tid % Fp;
  float val = (n < F) ? B[k * F + n] : 0.f;
  int kb = k >> 5, kr = k & 31;
  int lane = ((kr >> 3) << 4) | (n & 15);
  int j = kr & 7;
  int nb = n >> 4;
  size_t off = ((size_t)(kb * (Fp / 16) + nb) * 64 + lane) * 8 + j;
  Bp[off] = f2bf(val);
}

// W_att [8][256][32] -> logical B[k][n], n = h*32+j2
__global__ void pack_watt_frag(const float* __restrict__ W_att, ushort* __restrict__ Bp) {
  int tid = blockIdx.x * blockDim.x + threadIdx.x;
  if (tid >= 256 * 256) return;
  int k = tid >> 8, n = tid & 255;
  float val = W_att[(size_t)(n >> 5) * 8192 + k * 32 + (n & 31)];
  int kb = k >> 5, kr = k & 31;
  int lane = ((kr >> 3) << 4) | (n & 15);
  int j = kr & 7;
  int nb = n >> 4;
  size_t off = ((size_t)(kb * 16 + nb) * 64 + lane) * 8 + j;
  Bp[off] = f2bf(val);
}

// ---------------- bf16 MFMA GEMM: C[N,F] = A[N,256] @ B[256,F] (+bias) ----------------
// BM=32, 512 threads (8 waves: 2 row-groups x 4 col-groups), 16 KiB LDS.
// OUTMODE: 0 = f32 only, 1 = f32 + bf16 copy, 2 = bf16 only
template <int Fp, int F, int OUTMODE, bool BIAS, bool BFIN>
__global__ __launch_bounds__(512) void gemm_mfma(const float* __restrict__ A,
                                                 const ushort* __restrict__ Ab,
                                                 const ushort* __restrict__ Bp,
                                                 const float* __restrict__ bias,
                                                 float* __restrict__ C,
                                                 ushort* __restrict__ Cb, int N) {
  constexpr int NB = Fp / 64;
  __shared__ ushort lhs[32 * 256];
  int n0 = blockIdx.x * 32;
  int t = threadIdx.x;
  {
    int r = t >> 4, q = t & 15;
    int row = n0 + r;
    bool rin = row < N;
#pragma unroll
    for (int i = 0; i < 2; ++i) {
      int c0 = q * 16 + i * 8;
      int c8 = (c0 >> 3) ^ (r & 7);
      if (BFIN) {
        u16x8 hv = (u16x8){0, 0, 0, 0, 0, 0, 0, 0};
        if (rin) hv = *reinterpret_cast<const u16x8*>(Ab + (size_t)row * 256 + c0);
        *reinterpret_cast<u16x8*>(&lhs[r * 256 + c8 * 8]) = hv;
      } else {
        float4 f0 = {0.f, 0.f, 0.f, 0.f}, f1 = {0.f, 0.f, 0.f, 0.f};
        if (rin) {
          f0 = *reinterpret_cast<const float4*>(A + (size_t)row * 256 + c0);
          f1 = *reinterpret_cast<const float4*>(A + (size_t)row * 256 + c0 + 4);
        }
        float ff[8] = {f0.x, f0.y, f0.z, f0.w, f1.x, f1.y, f1.z, f1.w};
        short8 sh;
#pragma unroll
        for (int j = 0; j < 8; ++j) sh[j] = (short)f2bf(ff[j]);
        *reinterpret_cast<short8*>(&lhs[r * 256 + c8 * 8]) = sh;
      }
    }
  }
  __syncthreads();
  int w = t >> 6, l = t & 63;
  int wr = w >> 2, wc = w & 3;
  int lr = l & 15, lk = l >> 4;
  f32x4 acc[NB];
#pragma unroll
  for (int nb = 0; nb < NB; ++nb) acc[nb] = (f32x4){0.f, 0.f, 0.f, 0.f};

#pragma unroll
  for (int ks = 0; ks < 8; ++ks) {
    int row = wr * 16 + lr;
    int c8 = (ks * 4 + lk) ^ (row & 7);
    bf16x8 ah = *reinterpret_cast<const bf16x8*>(&lhs[row * 256 + c8 * 8]);
#pragma unroll
    for (int nb = 0; nb < NB; ++nb) {
      size_t off = ((size_t)(ks * (Fp / 16) + wc * NB + nb) * 64 + l) * 8;
      bf16x8 bh = *reinterpret_cast<const bf16x8*>(&Bp[off]);
      acc[nb] = __builtin_amdgcn_mfma_f32_16x16x32_bf16(ah, bh, acc[nb], 0, 0, 0);
    }
  }
  int rowbase = n0 + wr * 16 + lk * 4;
#pragma unroll
  for (int nb = 0; nb < NB; ++nb) {
    int col = wc * (NB * 16) + nb * 16 + lr;
    if (col < F) {
      float bi = BIAS ? bias[col] : 0.f;
#pragma unroll
      for (int rg = 0; rg < 4; ++rg) {
        if (rowbase + rg < N) {
          float v = acc[nb][rg] + bi;
          if (OUTMODE != 2) C[(size_t)(rowbase + rg) * F + col] = v;
          if (OUTMODE != 0) Cb[(size_t)(rowbase + rg) * F + col] = f2bf(v);
        }
      }
    }
  }
}

// ---------------- s1/s2 per node per head (bf16 H input) ----------------
__global__ void calc_s12(const ushort* __restrict__ Hb, const float* __restrict__ a1,
                         const float* __restrict__ a2, float* __restrict__ s1,
                         float* __restrict__ s2, int N) {
  int tid = blockIdx.x * blockDim.x + threadIdx.x;
  if (tid >= N * 8) return;
  int h = tid & 7;
  int n = tid >> 3;
  const ushort* hp = Hb + (size_t)n * 256 + h * 32;
  const float* A1 = a1 + h * 32;
  const float* A2 = a2 + h * 32;
  float d1 = 0.f, d2 = 0.f;
#pragma unroll
  for (int j0 = 0; j0 < 32; j0 += 8) {
    u16x8 hv = *reinterpret_cast<const u16x8*>(hp + j0);
#pragma unroll
    for (int j = 0; j < 8; ++j) {
      float v = bf2f(hv[j]);
      d1 = fmaf(v, A1[j0 + j], d1);
      d2 = fmaf(v, A2[j0 + j], d2);
    }
  }
  s1[tid] = d1;
  s2[tid] = d2;
}

__global__ void calc_s12_out(const float* __restrict__ Ho, const float* __restrict__ a1o,
                             const float* __restrict__ a2o, float* __restrict__ s1o,
                             float* __restrict__ s2o, int N) {
  int n = blockIdx.x * blockDim.x + threadIdx.x;
  if (n >= N) return;
  const float* hp = Ho + (size_t)n * 40;
  float d1 = 0.f, d2 = 0.f;
#pragma unroll
  for (int j = 0; j < 40; ++j) {
    float v = hp[j];
    d1 = fmaf(v, a1o[j], d1);
    d2 = fmaf(v, a2o[j], d2);
  }
  s1o[n] = d1;
  s2o[n] = d2;
}

// ---------------- CSR build ----------------
__global__ void hist_deg(const int* __restrict__ row, int* __restrict__ deg, int E) {
  int e = blockIdx.x * blockDim.x + threadIdx.x;
  if (e < E) atomicAdd(&deg[row[e]], 1);
}

__global__ void scan1(const int* __restrict__ deg, int* __restrict__ rp, int* __restrict__ bsum,
                      int N) {
  __shared__ int sd[256];
  int t = threadIdx.x;
  int i = blockIdx.x * 256 + t;
  int v = (i < N) ? deg[i] : 0;
  sd[t] = v;
  __syncthreads();
  for (int off = 1; off < 256; off <<= 1) {
    int x = (t >= off) ? sd[t - off] : 0;
    __syncthreads();
    sd[t] += x;
    __syncthreads();
  }
  if (i < N) rp[i] = sd[t] - v;
  if (t == 255) bsum[blockIdx.x] = sd[255];
}

__global__ void scan2(int* __restrict__ bsum, int nb) {
  __shared__ int sd[256];
  int t = threadIdx.x;
  int v = (t < nb) ? bsum[t] : 0;
  sd[t] = v;
  __syncthreads();
  for (int off = 1; off < 256; off <<= 1) {
    int x = (t >= off) ? sd[t - off] : 0;
    __syncthreads();
    sd[t] += x;
    __syncthreads();
  }
  if (t < nb) bsum[t] = sd[t] - v;
}

__global__ void scan3(int* __restrict__ rp, const int* __restrict__ bsum, int N, int E) {
  int i = blockIdx.x * 256 + threadIdx.x;
  if (i < N) rp[i] += bsum[blockIdx.x];
  if (i == 0) rp[N] = E;
}

__global__ void scatter_edges(const int* __restrict__ row, const int* __restrict__ col,
                              const int* __restrict__ rp, int* __restrict__ cur,
                              int* __restrict__ scol, int* __restrict__ srow, int E) {
  int e = blockIdx.x * blockDim.x + threadIdx.x;
  if (e >= E) return;
  int r = row[e];
  int p = atomicAdd(&cur[r], 1);
  int idx = rp[r] + p;
  scol[idx] = col[e];
  srow[idx] = r;
}

// ---------------- output-head edge weights (parallel) ----------------
__global__ void edge_wo(const int* __restrict__ srow, const int* __restrict__ scol,
                        const float* __restrict__ s1o, const float* __restrict__ s2o,
                        float* __restrict__ wo, int E) {
  int e = blockIdx.x * blockDim.x + threadIdx.x;
  if (e >= E) return;
  float lg = s1o[srow[e]] + s2o[scol[e]];
  float lr = lg > 0.f ? lg : 0.2f * lg;
  wo[e] = expf(-lr);
}

// ---------------- GAT layer-1 aggregation (fused edge weights): one wave/node ----------------
__global__ __launch_bounds__(64) void agg_att(const ushort* __restrict__ Hb,
                                              const float* __restrict__ s1,
                                              const float* __restrict__ s2,
                                              const int* __restrict__ rp,
                                              const int* __restrict__ scol,
                                              ushort* __restrict__ h1b, int N) {
  int n = blockIdx.x;
  int t = threadIdx.x;          // features t*4..t*4+3 ; head = t>>3
  int head = t >> 3;
  float s1n = s1[n * 8 + head];
  float acc[4] = {0.f, 0.f, 0.f, 0.f};
  float rs = 0.f;
  int beg = rp[n], end = rp[n + 1];
  for (int i = beg; i < end; ++i) {
    int c = scol[i];
    float lg = s1n + s2[c * 8 + head];
    float lr = lg > 0.f ? lg : 0.2f * lg;
    float wv = expf(-lr);
    rs += wv;
    const u16x4 hv = *reinterpret_cast<const u16x4*>(Hb + (size_t)c * 256 + t * 4);
#pragma unroll
    for (int j = 0; j < 4; ++j) acc[j] = fmaf(wv, bf2f(hv[j]), acc[j]);
  }
  float inv = 1.f / (rs + 1e-16f);
  u16x4 ov;
#pragma unroll
  for (int j = 0; j < 4; ++j) {
    float v = acc[j] * inv;
    v = v > 0.f ? v : expm1f(v);
    ov[j] = f2bf(v);
  }
  *reinterpret_cast<u16x4*>(h1b + (size_t)n * 256 + t * 4) = ov;
}

// ---------------- GraphConv aggregation: one wave/node ----------------
__global__ __launch_bounds__(64) void agg_gc(const ushort* __restrict__ Sb,
                                             const int* __restrict__ rp,
                                             const int* __restrict__ scol,
                                             const float* __restrict__ b_gc,
                                             ushort* __restrict__ h2b, int N) {
  int n = blockIdx.x;
  int t = threadIdx.x;
  float acc[4] = {0.f, 0.f, 0.f, 0.f};
  int beg = rp[n], end = rp[n + 1];
  for (int i = beg; i < end; ++i) {
    int c = scol[i];
    const u16x4 sv = *reinterpret_cast<const u16x4*>(Sb + (size_t)c * 256 + t * 4);
#pragma unroll
    for (int j = 0; j < 4; ++j) acc[j] += bf2f(sv[j]);
  }
  const float4 bv = *reinterpret_cast<const float4*>(b_gc + t * 4);
  float o[4] = {acc[0] + bv.x, acc[1] + bv.y, acc[2] + bv.z, acc[3] + bv.w};
  u16x4 ov;
#pragma unroll
  for (int j = 0; j < 4; ++j) ov[j] = f2bf(o[j]);
  *reinterpret_cast<u16x4*>(h2b + (size_t)n * 256 + t * 4) = ov;
}

// ---------------- output head aggregation + elu + log_softmax ----------------
__global__ __launch_bounds__(64) void agg_out_lsm(const ushort* __restrict__ Hob,
                                                  const float* __restrict__ wo,
                                                  const int* __restrict__ rp,
                                                  const int* __restrict__ scol,
                                                  float* __restrict__ out0, int N) {
  int n = blockIdx.x;
  int t = threadIdx.x;
  float acc = 0.f, rs = 0.f;
  int beg = rp[n], end = rp[n + 1];
  for (int i = beg; i < end; ++i) {
    int c = scol[i];
    float wv = wo[i];
    rs += wv;
    if (t < 40) acc = fmaf(wv, bf2f(Hob[(size_t)c * 40 + t]), acc);
  }
  float hp = acc / (rs + 1e-16f);
  float xo = (t < 40) ? (hp > 0.f ? hp : expm1f(hp)) : -3.0e38f;
  float mx = xo;
#pragma unroll
  for (int m = 1; m < 64; m <<= 1) mx = fmaxf(mx, __shfl_xor(mx, m));
  float ex = (t < 40) ? expf(xo - mx) : 0.f;
  float sum = ex;
#pragma unroll
  for (int m = 1; m < 64; m <<= 1) sum += __shfl_xor(sum, m);
  if (t < 40) out0[(size_t)n * 40 + t] = xo - mx - logf(sum);
}

// ---------------- launch ----------------
extern "C" void kernel_launch(void* const* d_in, const int* in_sizes, int n_in,
                              void* d_out, int out_size, void* d_ws, size_t ws_size,
                              hipStream_t stream) {
  const float* x      = (const float*)d_in[0];
  const int*   ei     = (const int*)d_in[1];
  const float* W_att  = (const float*)d_in[2];
  const float* a1     = (const float*)d_in[3];
  const float* a2     = (const float*)d_in[4];
  const float* W_out  = (const float*)d_in[5];
  const float* a1_out = (const float*)d_in[6];
  const float* a2_out = (const float*)d_in[7];
  const float* W_gc   = (const float*)d_in[8];
  const float* b_gc   = (const float*)d_in[9];
  const float* W_enc  = (const float*)d_in[10];
  const float* b_enc  = (const float*)d_in[11];

  const int N = in_sizes[0] / 256;
  const int E = in_sizes[1] / 2;
  const int* row = ei;
  const int* col = ei + E;

  char* p = (char*)d_ws;
  auto alloc = [&](size_t bytes) -> void* {
    void* r = (void*)p;
    p += (bytes + 255) & ~(size_t)255;
    return r;
  };
  ushort* hbuf = (ushort*)alloc((size_t)N * 256 * 2);  // bf16: H, then support
  ushort* h1b  = (ushort*)alloc((size_t)N * 256 * 2);
  ushort* h2b  = (ushort*)alloc((size_t)N * 256 * 2);
  float* Ho   = (float*)alloc((size_t)N * 40 * 4);
  ushort* Hob = (ushort*)alloc((size_t)N * 40 * 2);
  float* s1   = (float*)alloc((size_t)N * 8 * 4);
  float* s2   = (float*)alloc((size_t)N * 8 * 4);
  float* s1o  = (float*)alloc((size_t)N * 4);
  float* s2o  = (float*)alloc((size_t)N * 4);
  int* deg    = (int*)alloc((size_t)N * 4);
  int* rp     = (int*)alloc((size_t)(N + 1) * 4);
  int* bsum   = (int*)alloc(256 * 4);
  int* scol   = (int*)alloc((size_t)E * 4);
  int* srow   = (int*)alloc((size_t)E * 4);
  float* wo   = (float*)alloc((size_t)E * 4);
  ushort* Bp  = (ushort*)alloc((size_t)65536 * 2);
  ushort* Wg  = (ushort*)alloc((size_t)65536 * 2);
  ushort* We  = (ushort*)alloc((size_t)32768 * 2);
  ushort* Wo  = (ushort*)alloc((size_t)16384 * 2);

  float* out0 = (float*)d_out;
  float* outY = out0 + (size_t)N * 40;
  float* outZ = outY + (size_t)N * 128;

  const int nb = (N + 255) / 256;
  const int gblk = (N + 31) / 32;

  // weight packing
  pack_watt_frag<<<dim3(256), dim3(256), 0, stream>>>(W_att, Bp);
  pack_b<256, 256><<<dim3(256), dim3(256), 0, stream>>>(W_gc, Wg);
  pack_b<128, 128><<<dim3(128), dim3(256), 0, stream>>>(W_enc, We);
  pack_b<40, 64><<<dim3(64), dim3(256), 0, stream>>>(W_out, Wo);

  // CSR build (counting sort by row)
  hipMemsetAsync(deg, 0, (size_t)N * 4, stream);
  hist_deg<<<dim3((E + 255) / 256), dim3(256), 0, stream>>>(row, deg, E);
  scan1<<<dim3(nb), dim3(256), 0, stream>>>(deg, rp, bsum, N);
  scan2<<<dim3(1), dim3(256), 0, stream>>>(bsum, nb);
  scan3<<<dim3(nb), dim3(256), 0, stream>>>(rp, bsum, N, E);
  hipMemsetAsync(deg, 0, (size_t)N * 4, stream);  // reuse as cursor
  scatter_edges<<<dim3((E + 255) / 256), dim3(256), 0, stream>>>(row, col, rp, deg, scol, srow, E);

  // layer 1: H = x @ W_att(all heads), bf16 out
  gemm_mfma<256, 256, 2, false, false><<<dim3(gblk), dim3(512), 0, stream>>>(
      x, nullptr, Bp, nullptr, nullptr, hbuf, N);
  calc_s12<<<dim3((N * 8 + 255) / 256), dim3(256), 0, stream>>>(hbuf, a1, a2, s1, s2, N);
  agg_att<<<dim3(N), dim3(64), 0, stream>>>(hbuf, s1, s2, rp, scol, h1b, N);

  // GraphConv: support bf16 (overwrites hbuf)
  gemm_mfma<256, 256, 2, false, true><<<dim3(gblk), dim3(512), 0, stream>>>(
      nullptr, h1b, Wg, nullptr, nullptr, hbuf, N);
  agg_gc<<<dim3(N), dim3(64), 0, stream>>>(hbuf, rp, scol, b_gc, h2b, N);

  // output head: Ho f32 (for s12o) + bf16 copy (for gather)
  gemm_mfma<64, 40, 1, false, true><<<dim3(gblk), dim3(512), 0, stream>>>(
      nullptr, h2b, Wo, nullptr, Ho, Hob, N);
  calc_s12_out<<<dim3((N + 255) / 256), dim3(256), 0, stream>>>(Ho, a1_out, a2_out, s1o, s2o, N);
  edge_wo<<<dim3((E + 255) / 256), dim3(256), 0, stream>>>(srow, scol, s1o, s2o, wo, E);
  agg_out_lsm<<<dim3(N), dim3(64), 0, stream>>>(Hob, wo, rp, scol, out0, N);

  // y, z
  gemm_mfma<128, 128, 0, true, true><<<dim3(gblk), dim3(512), 0, stream>>>(
      nullptr, h1b, We, b_enc, outY, nullptr, N);
  gemm_mfma<128, 128, 0, true, true><<<dim3(gblk), dim3(512), 0, stream>>>(
      nullptr, h2b, We, b_enc, outZ, nullptr, N);
}

// Round 14
// 405.312 us; speedup vs baseline: 1.2010x; 1.0191x over previous
//
#include <hip/hip_runtime.h>
#include <math.h>

// N=50000, E=800000, nfeat=256, hid=256, nclass=40, nstruc=128, heads=8
typedef __attribute__((ext_vector_type(8))) short short8;
typedef __attribute__((ext_vector_type(4))) ushort u16x4;
typedef __attribute__((ext_vector_type(8))) ushort u16x8;
typedef __attribute__((ext_vector_type(8))) __bf16 bf16x8;
typedef __attribute__((ext_vector_type(4))) float f32x4;

__device__ inline ushort f2bf(float x) {
  union { float f; unsigned u; } v; v.f = x;
  unsigned r = v.u + 0x7fff + ((v.u >> 16) & 1);
  return (ushort)(r >> 16);
}
__device__ inline float bf2f(ushort b) {
  union { unsigned u; float f; } v; v.u = (unsigned)b << 16; return v.f;
}

// ---------------- fused weight packing (all 4 weights, one launch) ----------------
// frag order: off = ((kb*(Fp/16)+nb)*64 + lane)*8 + j ; lane=(kr>>3)*16|(n&15), j=kr&7
__device__ inline void pack_one(float val, int k, int n, int Fp, ushort* __restrict__ dst) {
  int kb = k >> 5, kr = k & 31;
  int lane = ((kr >> 3) << 4) | (n & 15);
  int j = kr & 7;
  int nb = n >> 4;
  size_t off = ((size_t)(kb * (Fp / 16) + nb) * 64 + lane) * 8 + j;
  dst[off] = f2bf(val);
}

__global__ void pack_all(const float* __restrict__ W_att, const float* __restrict__ W_gc,
                         const float* __restrict__ W_enc, const float* __restrict__ W_out,
                         ushort* __restrict__ Bp, ushort* __restrict__ Wg,
                         ushort* __restrict__ We, ushort* __restrict__ Wo) {
  int tid = blockIdx.x * blockDim.x + threadIdx.x;
  if (tid < 65536) {  // W_att [8][256][32] -> B[k][n], n=h*32+j2, Fp=256
    int k = tid >> 8, n = tid & 255;
    float val = W_att[(size_t)(n >> 5) * 8192 + k * 32 + (n & 31)];
    pack_one(val, k, n, 256, Bp);
  } else if (tid < 131072) {  // W_gc [256][256], Fp=256
    int t2 = tid - 65536;
    int k = t2 >> 8, n = t2 & 255;
    pack_one(W_gc[k * 256 + n], k, n, 256, Wg);
  } else if (tid < 163840) {  // W_enc [256][128], Fp=128
    int t2 = tid - 131072;
    int k = t2 >> 7, n = t2 & 127;
    pack_one(W_enc[k * 128 + n], k, n, 128, We);
  } else if (tid < 180224) {  // W_out [256][40] pad to 64, Fp=64
    int t2 = tid - 163840;
    int k = t2 >> 6, n = t2 & 63;
    float val = (n < 40) ? W_out[k * 40 + n] : 0.f;
    pack_one(val, k, n, 64, Wo);
  }
}

// ---------------- bf16 MFMA GEMM: C[N,F] = A[N,256] @ B[256,F] (+bias) ----------------
// BM=64, 512 threads (8 waves: 2 row-groups x 4 col-groups), 2 row-frags/wave, 32 KiB LDS.
// OUTMODE: 0 = f32 only, 1 = f32 + bf16 copy, 2 = bf16 only
template <int Fp, int F, int OUTMODE, bool BIAS, bool BFIN>
__global__ __launch_bounds__(512) void gemm_mfma(const float* __restrict__ A,
                                                 const ushort* __restrict__ Ab,
                                                 const ushort* __restrict__ Bp,
                                                 const float* __restrict__ bias,
                                                 float* __restrict__ C,
                                                 ushort* __restrict__ Cb, int N) {
  constexpr int NB = Fp / 64;
  __shared__ ushort lhs[64 * 256];
  int n0 = blockIdx.x * 64;
  int t = threadIdx.x;
  // ---- stage A tile (64x256 bf16, XOR-swizzled 16B units) ----
  {
    int r = t >> 3, q = t & 7;   // 8 threads/row, 32 cols each
    int row = n0 + r;
    bool rin = row < N;
#pragma unroll
    for (int i = 0; i < 4; ++i) {
      int c0 = q * 32 + i * 8;
      int c8 = (c0 >> 3) ^ (r & 7);
      if (BFIN) {
        u16x8 hv = (u16x8){0, 0, 0, 0, 0, 0, 0, 0};
        if (rin) hv = *reinterpret_cast<const u16x8*>(Ab + (size_t)row * 256 + c0);
        *reinterpret_cast<u16x8*>(&lhs[r * 256 + c8 * 8]) = hv;
      } else {
        float4 f0 = {0.f, 0.f, 0.f, 0.f}, f1 = {0.f, 0.f, 0.f, 0.f};
        if (rin) {
          f0 = *reinterpret_cast<const float4*>(A + (size_t)row * 256 + c0);
          f1 = *reinterpret_cast<const float4*>(A + (size_t)row * 256 + c0 + 4);
        }
        float ff[8] = {f0.x, f0.y, f0.z, f0.w, f1.x, f1.y, f1.z, f1.w};
        short8 sh;
#pragma unroll
        for (int j = 0; j < 8; ++j) sh[j] = (short)f2bf(ff[j]);
        *reinterpret_cast<short8*>(&lhs[r * 256 + c8 * 8]) = sh;
      }
    }
  }
  __syncthreads();
  // ---- compute: wave (wr,wc); 2 row-frags x NB col-frags ----
  int w = t >> 6, l = t & 63;
  int wr = w >> 2, wc = w & 3;
  int lr = l & 15, lk = l >> 4;
  f32x4 acc[2][NB];
#pragma unroll
  for (int m = 0; m < 2; ++m)
#pragma unroll
    for (int nb = 0; nb < NB; ++nb) acc[m][nb] = (f32x4){0.f, 0.f, 0.f, 0.f};

#pragma unroll
  for (int ks = 0; ks < 8; ++ks) {
    bf16x8 ah[2];
#pragma unroll
    for (int m = 0; m < 2; ++m) {
      int row = wr * 32 + m * 16 + lr;
      int c8 = (ks * 4 + lk) ^ (row & 7);
      ah[m] = *reinterpret_cast<const bf16x8*>(&lhs[row * 256 + c8 * 8]);
    }
#pragma unroll
    for (int nb = 0; nb < NB; ++nb) {
      size_t off = ((size_t)(ks * (Fp / 16) + wc * NB + nb) * 64 + l) * 8;
      bf16x8 bh = *reinterpret_cast<const bf16x8*>(&Bp[off]);
#pragma unroll
      for (int m = 0; m < 2; ++m)
        acc[m][nb] = __builtin_amdgcn_mfma_f32_16x16x32_bf16(ah[m], bh, acc[m][nb], 0, 0, 0);
    }
  }
  // ---- write C: col=lane&15, row=(lane>>4)*4+reg ----
#pragma unroll
  for (int m = 0; m < 2; ++m) {
    int rowbase = n0 + wr * 32 + m * 16 + lk * 4;
#pragma unroll
    for (int nb = 0; nb < NB; ++nb) {
      int col = wc * (NB * 16) + nb * 16 + lr;
      if (col < F) {
        float bi = BIAS ? bias[col] : 0.f;
#pragma unroll
        for (int rg = 0; rg < 4; ++rg) {
          if (rowbase + rg < N) {
            float v = acc[m][nb][rg] + bi;
            if (OUTMODE != 2) C[(size_t)(rowbase + rg) * F + col] = v;
            if (OUTMODE != 0) Cb[(size_t)(rowbase + rg) * F + col] = f2bf(v);
          }
        }
      }
    }
  }
}

// ---------------- s1/s2 per node per head (bf16 H input) ----------------
__global__ void calc_s12(const ushort* __restrict__ Hb, const float* __restrict__ a1,
                         const float* __restrict__ a2, float* __restrict__ s1,
                         float* __restrict__ s2, int N) {
  int tid = blockIdx.x * blockDim.x + threadIdx.x;
  if (tid >= N * 8) return;
  int h = tid & 7;
  int n = tid >> 3;
  const ushort* hp = Hb + (size_t)n * 256 + h * 32;
  const float* A1 = a1 + h * 32;
  const float* A2 = a2 + h * 32;
  float d1 = 0.f, d2 = 0.f;
#pragma unroll
  for (int j0 = 0; j0 < 32; j0 += 8) {
    u16x8 hv = *reinterpret_cast<const u16x8*>(hp + j0);
#pragma unroll
    for (int j = 0; j < 8; ++j) {
      float v = bf2f(hv[j]);
      d1 = fmaf(v, A1[j0 + j], d1);
      d2 = fmaf(v, A2[j0 + j], d2);
    }
  }
  s1[tid] = d1;
  s2[tid] = d2;
}

__global__ void calc_s12_out(const float* __restrict__ Ho, const float* __restrict__ a1o,
                             const float* __restrict__ a2o, float* __restrict__ s1o,
                             float* __restrict__ s2o, int N) {
  int n = blockIdx.x * blockDim.x + threadIdx.x;
  if (n >= N) return;
  const float* hp = Ho + (size_t)n * 40;
  float d1 = 0.f, d2 = 0.f;
#pragma unroll
  for (int j = 0; j < 40; ++j) {
    float v = hp[j];
    d1 = fmaf(v, a1o[j], d1);
    d2 = fmaf(v, a2o[j], d2);
  }
  s1o[n] = d1;
  s2o[n] = d2;
}

// ---------------- CSR build ----------------
__global__ void hist_deg(const int* __restrict__ row, int* __restrict__ deg, int E) {
  int e = blockIdx.x * blockDim.x + threadIdx.x;
  if (e < E) atomicAdd(&deg[row[e]], 1);
}

__global__ void scan1(const int* __restrict__ deg, int* __restrict__ rp, int* __restrict__ bsum,
                      int N) {
  __shared__ int sd[256];
  int t = threadIdx.x;
  int i = blockIdx.x * 256 + t;
  int v = (i < N) ? deg[i] : 0;
  sd[t] = v;
  __syncthreads();
  for (int off = 1; off < 256; off <<= 1) {
    int x = (t >= off) ? sd[t - off] : 0;
    __syncthreads();
    sd[t] += x;
    __syncthreads();
  }
  if (i < N) rp[i] = sd[t] - v;
  if (t == 255) bsum[blockIdx.x] = sd[255];
}

__global__ void scan2(int* __restrict__ bsum, int nb) {
  __shared__ int sd[256];
  int t = threadIdx.x;
  int v = (t < nb) ? bsum[t] : 0;
  sd[t] = v;
  __syncthreads();
  for (int off = 1; off < 256; off <<= 1) {
    int x = (t >= off) ? sd[t - off] : 0;
    __syncthreads();
    sd[t] += x;
    __syncthreads();
  }
  if (t < nb) bsum[t] = sd[t] - v;
}

__global__ void scan3(int* __restrict__ rp, const int* __restrict__ bsum, int N, int E) {
  int i = blockIdx.x * 256 + threadIdx.x;
  if (i < N) rp[i] += bsum[blockIdx.x];
  if (i == 0) rp[N] = E;
}

__global__ void scatter_edges(const int* __restrict__ row, const int* __restrict__ col,
                              const int* __restrict__ rp, int* __restrict__ cur,
                              int* __restrict__ scol, int* __restrict__ srow, int E) {
  int e = blockIdx.x * blockDim.x + threadIdx.x;
  if (e >= E) return;
  int r = row[e];
  int p = atomicAdd(&cur[r], 1);
  int idx = rp[r] + p;
  scol[idx] = col[e];
  srow[idx] = r;
}

// ---------------- output-head edge weights (parallel) ----------------
__global__ void edge_wo(const int* __restrict__ srow, const int* __restrict__ scol,
                        const float* __restrict__ s1o, const float* __restrict__ s2o,
                        float* __restrict__ wo, int E) {
  int e = blockIdx.x * blockDim.x + threadIdx.x;
  if (e >= E) return;
  float lg = s1o[srow[e]] + s2o[scol[e]];
  float lr = lg > 0.f ? lg : 0.2f * lg;
  wo[e] = expf(-lr);
}

// ---------------- GAT layer-1 aggregation (fused edge weights): one wave/node ----------------
__global__ __launch_bounds__(64) void agg_att(const ushort* __restrict__ Hb,
                                              const float* __restrict__ s1,
                                              const float* __restrict__ s2,
                                              const int* __restrict__ rp,
                                              const int* __restrict__ scol,
                                              ushort* __restrict__ h1b, int N) {
  int n = blockIdx.x;
  int t = threadIdx.x;          // features t*4..t*4+3 ; head = t>>3
  int head = t >> 3;
  float s1n = s1[n * 8 + head];
  float acc[4] = {0.f, 0.f, 0.f, 0.f};
  float rs = 0.f;
  int beg = rp[n], end = rp[n + 1];
  for (int i = beg; i < end; ++i) {
    int c = scol[i];
    float lg = s1n + s2[c * 8 + head];
    float lr = lg > 0.f ? lg : 0.2f * lg;
    float wv = expf(-lr);
    rs += wv;
    const u16x4 hv = *reinterpret_cast<const u16x4*>(Hb + (size_t)c * 256 + t * 4);
#pragma unroll
    for (int j = 0; j < 4; ++j) acc[j] = fmaf(wv, bf2f(hv[j]), acc[j]);
  }
  float inv = 1.f / (rs + 1e-16f);
  u16x4 ov;
#pragma unroll
  for (int j = 0; j < 4; ++j) {
    float v = acc[j] * inv;
    v = v > 0.f ? v : expm1f(v);
    ov[j] = f2bf(v);
  }
  *reinterpret_cast<u16x4*>(h1b + (size_t)n * 256 + t * 4) = ov;
}

// ---------------- GraphConv aggregation: one wave/node ----------------
__global__ __launch_bounds__(64) void agg_gc(const ushort* __restrict__ Sb,
                                             const int* __restrict__ rp,
                                             const int* __restrict__ scol,
                                             const float* __restrict__ b_gc,
                                             ushort* __restrict__ h2b, int N) {
  int n = blockIdx.x;
  int t = threadIdx.x;
  float acc[4] = {0.f, 0.f, 0.f, 0.f};
  int beg = rp[n], end = rp[n + 1];
  for (int i = beg; i < end; ++i) {
    int c = scol[i];
    const u16x4 sv = *reinterpret_cast<const u16x4*>(Sb + (size_t)c * 256 + t * 4);
#pragma unroll
    for (int j = 0; j < 4; ++j) acc[j] += bf2f(sv[j]);
  }
  const float4 bv = *reinterpret_cast<const float4*>(b_gc + t * 4);
  float o[4] = {acc[0] + bv.x, acc[1] + bv.y, acc[2] + bv.z, acc[3] + bv.w};
  u16x4 ov;
#pragma unroll
  for (int j = 0; j < 4; ++j) ov[j] = f2bf(o[j]);
  *reinterpret_cast<u16x4*>(h2b + (size_t)n * 256 + t * 4) = ov;
}

// ---------------- output head aggregation + elu + log_softmax ----------------
__global__ __launch_bounds__(64) void agg_out_lsm(const ushort* __restrict__ Hob,
                                                  const float* __restrict__ wo,
                                                  const int* __restrict__ rp,
                                                  const int* __restrict__ scol,
                                                  float* __restrict__ out0, int N) {
  int n = blockIdx.x;
  int t = threadIdx.x;
  float acc = 0.f, rs = 0.f;
  int beg = rp[n], end = rp[n + 1];
  for (int i = beg; i < end; ++i) {
    int c = scol[i];
    float wv = wo[i];
    rs += wv;
    if (t < 40) acc = fmaf(wv, bf2f(Hob[(size_t)c * 40 + t]), acc);
  }
  float hp = acc / (rs + 1e-16f);
  float xo = (t < 40) ? (hp > 0.f ? hp : expm1f(hp)) : -3.0e38f;
  float mx = xo;
#pragma unroll
  for (int m = 1; m < 64; m <<= 1) mx = fmaxf(mx, __shfl_xor(mx, m));
  float ex = (t < 40) ? expf(xo - mx) : 0.f;
  float sum = ex;
#pragma unroll
  for (int m = 1; m < 64; m <<= 1) sum += __shfl_xor(sum, m);
  if (t < 40) out0[(size_t)n * 40 + t] = xo - mx - logf(sum);
}

// ---------------- launch ----------------
extern "C" void kernel_launch(void* const* d_in, const int* in_sizes, int n_in,
                              void* d_out, int out_size, void* d_ws, size_t ws_size,
                              hipStream_t stream) {
  const float* x      = (const float*)d_in[0];
  const int*   ei     = (const int*)d_in[1];
  const float* W_att  = (const float*)d_in[2];
  const float* a1     = (const float*)d_in[3];
  const float* a2     = (const float*)d_in[4];
  const float* W_out  = (const float*)d_in[5];
  const float* a1_out = (const float*)d_in[6];
  const float* a2_out = (const float*)d_in[7];
  const float* W_gc   = (const float*)d_in[8];
  const float* b_gc   = (const float*)d_in[9];
  const float* W_enc  = (const float*)d_in[10];
  const float* b_enc  = (const float*)d_in[11];

  const int N = in_sizes[0] / 256;
  const int E = in_sizes[1] / 2;
  const int* row = ei;
  const int* col = ei + E;

  char* p = (char*)d_ws;
  auto alloc = [&](size_t bytes) -> void* {
    void* r = (void*)p;
    p += (bytes + 255) & ~(size_t)255;
    return r;
  };
  ushort* hbuf = (ushort*)alloc((size_t)N * 256 * 2);  // bf16: H, then support
  ushort* h1b  = (ushort*)alloc((size_t)N * 256 * 2 * 2);  // h1b ‖ h2b contiguous
  ushort* h2b  = h1b + (size_t)N * 256;
  float* Ho   = (float*)alloc((size_t)N * 40 * 4);
  ushort* Hob = (ushort*)alloc((size_t)N * 40 * 2);
  float* s1   = (float*)alloc((size_t)N * 8 * 4);
  float* s2   = (float*)alloc((size_t)N * 8 * 4);
  float* s1o  = (float*)alloc((size_t)N * 4);
  float* s2o  = (float*)alloc((size_t)N * 4);
  int* deg    = (int*)alloc((size_t)N * 4);
  int* rp     = (int*)alloc((size_t)(N + 1) * 4);
  int* bsum   = (int*)alloc(256 * 4);
  int* scol   = (int*)alloc((size_t)E * 4);
  int* srow   = (int*)alloc((size_t)E * 4);
  float* wo   = (float*)alloc((size_t)E * 4);
  ushort* Bp  = (ushort*)alloc((size_t)65536 * 2);
  ushort* Wg  = (ushort*)alloc((size_t)65536 * 2);
  ushort* We  = (ushort*)alloc((size_t)32768 * 2);
  ushort* Wo  = (ushort*)alloc((size_t)16384 * 2);

  float* out0 = (float*)d_out;
  float* outY = out0 + (size_t)N * 40;   // outZ = outY + N*128, contiguous

  const int nb = (N + 255) / 256;
  const int gblk = (N + 63) / 64;
  const int gblk2 = (2 * N + 63) / 64;

  // fused weight packing
  pack_all<<<dim3((180224 + 255) / 256), dim3(256), 0, stream>>>(
      W_att, W_gc, W_enc, W_out, Bp, Wg, We, Wo);

  // CSR build (counting sort by row)
  hipMemsetAsync(deg, 0, (size_t)N * 4, stream);
  hist_deg<<<dim3((E + 255) / 256), dim3(256), 0, stream>>>(row, deg, E);
  scan1<<<dim3(nb), dim3(256), 0, stream>>>(deg, rp, bsum, N);
  scan2<<<dim3(1), dim3(256), 0, stream>>>(bsum, nb);
  scan3<<<dim3(nb), dim3(256), 0, stream>>>(rp, bsum, N, E);
  hipMemsetAsync(deg, 0, (size_t)N * 4, stream);  // reuse as cursor
  scatter_edges<<<dim3((E + 255) / 256), dim3(256), 0, stream>>>(row, col, rp, deg, scol, srow, E);

  // layer 1: H = x @ W_att(all heads), bf16 out
  gemm_mfma<256, 256, 2, false, false><<<dim3(gblk), dim3(512), 0, stream>>>(
      x, nullptr, Bp, nullptr, nullptr, hbuf, N);
  calc_s12<<<dim3((N * 8 + 255) / 256), dim3(256), 0, stream>>>(hbuf, a1, a2, s1, s2, N);
  agg_att<<<dim3(N), dim3(64), 0, stream>>>(hbuf, s1, s2, rp, scol, h1b, N);

  // GraphConv: support bf16 (overwrites hbuf)
  gemm_mfma<256, 256, 2, false, true><<<dim3(gblk), dim3(512), 0, stream>>>(
      nullptr, h1b, Wg, nullptr, nullptr, hbuf, N);
  agg_gc<<<dim3(N), dim3(64), 0, stream>>>(hbuf, rp, scol, b_gc, h2b, N);

  // output head: Ho f32 (for s12o) + bf16 copy (for gather)
  gemm_mfma<64, 40, 1, false, true><<<dim3(gblk), dim3(512), 0, stream>>>(
      nullptr, h2b, Wo, nullptr, Ho, Hob, N);
  calc_s12_out<<<dim3((N + 255) / 256), dim3(256), 0, stream>>>(Ho, a1_out, a2_out, s1o, s2o, N);
  edge_wo<<<dim3((E + 255) / 256), dim3(256), 0, stream>>>(srow, scol, s1o, s2o, wo, E);
  agg_out_lsm<<<dim3(N), dim3(64), 0, stream>>>(Hob, wo, rp, scol, out0, N);

  // y ‖ z in one GEMM: [h1b;h2b] (2N rows, contiguous) @ W_enc -> outY‖outZ (contiguous)
  gemm_mfma<128, 128, 0, true, true><<<dim3(gblk2), dim3(512), 0, stream>>>(
      nullptr, h1b, We, b_enc, outY, nullptr, 2 * N);
}

// Round 15
// 402.081 us; speedup vs baseline: 1.2106x; 1.0080x over previous
//
#include <hip/hip_runtime.h>
#include <math.h>

// N=50000, E=800000, nfeat=256, hid=256, nclass=40, nstruc=128, heads=8
typedef __attribute__((ext_vector_type(8))) short short8;
typedef __attribute__((ext_vector_type(4))) ushort u16x4;
typedef __attribute__((ext_vector_type(8))) ushort u16x8;
typedef __attribute__((ext_vector_type(8))) __bf16 bf16x8;
typedef __attribute__((ext_vector_type(4))) float f32x4;

__device__ inline ushort f2bf(float x) {
  union { float f; unsigned u; } v; v.f = x;
  unsigned r = v.u + 0x7fff + ((v.u >> 16) & 1);
  return (ushort)(r >> 16);
}
__device__ inline float bf2f(ushort b) {
  union { unsigned u; float f; } v; v.u = (unsigned)b << 16; return v.f;
}

#define GLOAD_LDS16(g, l)                                                      \
  __builtin_amdgcn_global_load_lds(                                            \
      (const __attribute__((address_space(1))) void*)(g),                      \
      (__attribute__((address_space(3))) void*)(l), 16, 0, 0)

// ---------------- fused weight packing (all 4 weights, one launch) ----------------
__device__ inline void pack_one(float val, int k, int n, int Fp, ushort* __restrict__ dst) {
  int kb = k >> 5, kr = k & 31;
  int lane = ((kr >> 3) << 4) | (n & 15);
  int j = kr & 7;
  int nb = n >> 4;
  size_t off = ((size_t)(kb * (Fp / 16) + nb) * 64 + lane) * 8 + j;
  dst[off] = f2bf(val);
}

__global__ void pack_all(const float* __restrict__ W_att, const float* __restrict__ W_gc,
                         const float* __restrict__ W_enc, const float* __restrict__ W_out,
                         ushort* __restrict__ Bp, ushort* __restrict__ Wg,
                         ushort* __restrict__ We, ushort* __restrict__ Wo) {
  int tid = blockIdx.x * blockDim.x + threadIdx.x;
  if (tid < 65536) {
    int k = tid >> 8, n = tid & 255;
    float val = W_att[(size_t)(n >> 5) * 8192 + k * 32 + (n & 31)];
    pack_one(val, k, n, 256, Bp);
  } else if (tid < 131072) {
    int t2 = tid - 65536;
    int k = t2 >> 8, n = t2 & 255;
    pack_one(W_gc[k * 256 + n], k, n, 256, Wg);
  } else if (tid < 163840) {
    int t2 = tid - 131072;
    int k = t2 >> 7, n = t2 & 127;
    pack_one(W_enc[k * 128 + n], k, n, 128, We);
  } else if (tid < 180224) {
    int t2 = tid - 163840;
    int k = t2 >> 6, n = t2 & 63;
    float val = (n < 40) ? W_out[k * 40 + n] : 0.f;
    pack_one(val, k, n, 64, Wo);
  }
}

// ---------------- bf16 MFMA GEMM: C = A[.,256] @ B[256,F] (+bias) ----------------
// BM=64, 512 threads (8 waves: 2 row x 4 col groups), 2 row-frags/wave, 32 KiB LDS.
// BFIN: bf16 input staged via global_load_lds (linear LDS dest, pre-swizzled source).
// NPAD==0: normal (rows [0,Nv)). NPAD>0: merged-yz (y rows [0,Nv), z rows [NPAD,NPAD+Nv)).
template <int Fp, int F, int OUTMODE, bool BIAS, bool BFIN>
__global__ __launch_bounds__(512) void gemm_mfma(const float* __restrict__ A,
                                                 const ushort* __restrict__ Ab,
                                                 const ushort* __restrict__ Bp,
                                                 const float* __restrict__ bias,
                                                 float* __restrict__ C,
                                                 ushort* __restrict__ Cb, int Nv, int NPAD) {
  constexpr int NB = Fp / 64;
  __shared__ ushort lhs[64 * 256];
  int n0 = blockIdx.x * 64;
  int t = threadIdx.x;
  int wv = t >> 6, l = t & 63;
  // ---- stage A tile (64x256 bf16, XOR-swizzled 16B units) ----
  if (BFIN) {
    // linear LDS dest via global_load_lds; source pre-swizzled:
    // LDS unit (r, cs) holds source col-unit cs^(r&7).
#pragma unroll
    for (int i = 0; i < 4; ++i) {
      int u = i * 512 + wv * 64 + l;
      int r = u >> 5, cs = u & 31;
      int csrc = cs ^ (r & 7);
      const ushort* src = Ab + (size_t)(n0 + r) * 256 + csrc * 8;
      GLOAD_LDS16(src, lhs + (size_t)(i * 512 + wv * 64) * 8);
    }
  } else {
    int r = t >> 3, q = t & 7;
    int row = n0 + r;
    bool rin = row < Nv;
#pragma unroll
    for (int i = 0; i < 4; ++i) {
      int c0 = q * 32 + i * 8;
      int c8 = (c0 >> 3) ^ (r & 7);
      float4 f0 = {0.f, 0.f, 0.f, 0.f}, f1 = {0.f, 0.f, 0.f, 0.f};
      if (rin) {
        f0 = *reinterpret_cast<const float4*>(A + (size_t)row * 256 + c0);
        f1 = *reinterpret_cast<const float4*>(A + (size_t)row * 256 + c0 + 4);
      }
      float ff[8] = {f0.x, f0.y, f0.z, f0.w, f1.x, f1.y, f1.z, f1.w};
      short8 sh;
#pragma unroll
      for (int j = 0; j < 8; ++j) sh[j] = (short)f2bf(ff[j]);
      *reinterpret_cast<short8*>(&lhs[r * 256 + c8 * 8]) = sh;
    }
  }
  __syncthreads();
  // ---- compute: wave (wr,wc); 2 row-frags x NB col-frags ----
  int wr = wv >> 2, wc = wv & 3;
  int lr = l & 15, lk = l >> 4;
  f32x4 acc[2][NB];
#pragma unroll
  for (int m = 0; m < 2; ++m)
#pragma unroll
    for (int nb = 0; nb < NB; ++nb) acc[m][nb] = (f32x4){0.f, 0.f, 0.f, 0.f};

#pragma unroll
  for (int ks = 0; ks < 8; ++ks) {
    bf16x8 ah[2];
#pragma unroll
    for (int m = 0; m < 2; ++m) {
      int row = wr * 32 + m * 16 + lr;
      int c8 = (ks * 4 + lk) ^ (row & 7);
      ah[m] = *reinterpret_cast<const bf16x8*>(&lhs[row * 256 + c8 * 8]);
    }
#pragma unroll
    for (int nb = 0; nb < NB; ++nb) {
      size_t off = ((size_t)(ks * (Fp / 16) + wc * NB + nb) * 64 + l) * 8;
      bf16x8 bh = *reinterpret_cast<const bf16x8*>(&Bp[off]);
#pragma unroll
      for (int m = 0; m < 2; ++m)
        acc[m][nb] = __builtin_amdgcn_mfma_f32_16x16x32_bf16(ah[m], bh, acc[m][nb], 0, 0, 0);
    }
  }
  // ---- write C: col=lane&15, row=(lane>>4)*4+reg ----
#pragma unroll
  for (int m = 0; m < 2; ++m) {
    int rowbase = n0 + wr * 32 + m * 16 + lk * 4;
#pragma unroll
    for (int nb = 0; nb < NB; ++nb) {
      int col = wc * (NB * 16) + nb * 16 + lr;
      if (col < F) {
        float bi = BIAS ? bias[col] : 0.f;
#pragma unroll
        for (int rg = 0; rg < 4; ++rg) {
          int gr = rowbase + rg;
          int crow;
          bool ok;
          if (NPAD == 0) {
            crow = gr; ok = gr < Nv;
          } else if (gr < NPAD) {
            crow = gr; ok = gr < Nv;
          } else {
            int g2 = gr - NPAD;
            crow = Nv + g2; ok = g2 < Nv;
          }
          if (ok) {
            float v = acc[m][nb][rg] + bi;
            if (OUTMODE != 2) C[(size_t)crow * F + col] = v;
            if (OUTMODE != 0) Cb[(size_t)crow * F + col] = f2bf(v);
          }
        }
      }
    }
  }
}

// ---------------- s1/s2 per node per head (bf16 H input) ----------------
__global__ void calc_s12(const ushort* __restrict__ Hb, const float* __restrict__ a1,
                         const float* __restrict__ a2, float* __restrict__ s1,
                         float* __restrict__ s2, int N) {
  int tid = blockIdx.x * blockDim.x + threadIdx.x;
  if (tid >= N * 8) return;
  int h = tid & 7;
  int n = tid >> 3;
  const ushort* hp = Hb + (size_t)n * 256 + h * 32;
  const float* A1 = a1 + h * 32;
  const float* A2 = a2 + h * 32;
  float d1 = 0.f, d2 = 0.f;
#pragma unroll
  for (int j0 = 0; j0 < 32; j0 += 8) {
    u16x8 hv = *reinterpret_cast<const u16x8*>(hp + j0);
#pragma unroll
    for (int j = 0; j < 8; ++j) {
      float v = bf2f(hv[j]);
      d1 = fmaf(v, A1[j0 + j], d1);
      d2 = fmaf(v, A2[j0 + j], d2);
    }
  }
  s1[tid] = d1;
  s2[tid] = d2;
}

__global__ void calc_s12_out(const float* __restrict__ Ho, const float* __restrict__ a1o,
                             const float* __restrict__ a2o, float* __restrict__ s1o,
                             float* __restrict__ s2o, int N) {
  int n = blockIdx.x * blockDim.x + threadIdx.x;
  if (n >= N) return;
  const float* hp = Ho + (size_t)n * 40;
  float d1 = 0.f, d2 = 0.f;
#pragma unroll
  for (int j = 0; j < 40; ++j) {
    float v = hp[j];
    d1 = fmaf(v, a1o[j], d1);
    d2 = fmaf(v, a2o[j], d2);
  }
  s1o[n] = d1;
  s2o[n] = d2;
}

// ---------------- CSR build ----------------
__global__ void hist_deg(const int* __restrict__ row, int* __restrict__ deg, int E) {
  int e = blockIdx.x * blockDim.x + threadIdx.x;
  if (e < E) atomicAdd(&deg[row[e]], 1);
}

__global__ void scan1(const int* __restrict__ deg, int* __restrict__ rp, int* __restrict__ bsum,
                      int N) {
  __shared__ int sd[256];
  int t = threadIdx.x;
  int i = blockIdx.x * 256 + t;
  int v = (i < N) ? deg[i] : 0;
  sd[t] = v;
  __syncthreads();
  for (int off = 1; off < 256; off <<= 1) {
    int x = (t >= off) ? sd[t - off] : 0;
    __syncthreads();
    sd[t] += x;
    __syncthreads();
  }
  if (i < N) rp[i] = sd[t] - v;
  if (t == 255) bsum[blockIdx.x] = sd[255];
}

__global__ void scan2(int* __restrict__ bsum, int nb) {
  __shared__ int sd[256];
  int t = threadIdx.x;
  int v = (t < nb) ? bsum[t] : 0;
  sd[t] = v;
  __syncthreads();
  for (int off = 1; off < 256; off <<= 1) {
    int x = (t >= off) ? sd[t - off] : 0;
    __syncthreads();
    sd[t] += x;
    __syncthreads();
  }
  if (t < nb) bsum[t] = sd[t] - v;
}

__global__ void scan3(int* __restrict__ rp, const int* __restrict__ bsum, int N, int E) {
  int i = blockIdx.x * 256 + threadIdx.x;
  if (i < N) rp[i] += bsum[blockIdx.x];
  if (i == 0) rp[N] = E;
}

__global__ void scatter_edges(const int* __restrict__ row, const int* __restrict__ col,
                              const int* __restrict__ rp, int* __restrict__ cur,
                              int* __restrict__ scol, int* __restrict__ srow, int E) {
  int e = blockIdx.x * blockDim.x + threadIdx.x;
  if (e >= E) return;
  int r = row[e];
  int p = atomicAdd(&cur[r], 1);
  int idx = rp[r] + p;
  scol[idx] = col[e];
  srow[idx] = r;
}

// ---------------- output-head edge weights (parallel) ----------------
__global__ void edge_wo(const int* __restrict__ srow, const int* __restrict__ scol,
                        const float* __restrict__ s1o, const float* __restrict__ s2o,
                        float* __restrict__ wo, int E) {
  int e = blockIdx.x * blockDim.x + threadIdx.x;
  if (e >= E) return;
  float lg = s1o[srow[e]] + s2o[scol[e]];
  float lr = lg > 0.f ? lg : 0.2f * lg;
  wo[e] = expf(-lr);
}

// ---------------- GAT layer-1 aggregation (fused edge weights): one wave/node ----------------
__global__ __launch_bounds__(64) void agg_att(const ushort* __restrict__ Hb,
                                              const float* __restrict__ s1,
                                              const float* __restrict__ s2,
                                              const int* __restrict__ rp,
                                              const int* __restrict__ scol,
                                              ushort* __restrict__ h1b, int N) {
  int n = blockIdx.x;
  int t = threadIdx.x;          // features t*4..t*4+3 ; head = t>>3
  int head = t >> 3;
  float s1n = s1[n * 8 + head];
  float acc[4] = {0.f, 0.f, 0.f, 0.f};
  float rs = 0.f;
  int beg = rp[n], end = rp[n + 1];
  for (int i = beg; i < end; ++i) {
    int c = scol[i];
    float lg = s1n + s2[c * 8 + head];
    float lr = lg > 0.f ? lg : 0.2f * lg;
    float wv = expf(-lr);
    rs += wv;
    const u16x4 hv = *reinterpret_cast<const u16x4*>(Hb + (size_t)c * 256 + t * 4);
#pragma unroll
    for (int j = 0; j < 4; ++j) acc[j] = fmaf(wv, bf2f(hv[j]), acc[j]);
  }
  float inv = 1.f / (rs + 1e-16f);
  u16x4 ov;
#pragma unroll
  for (int j = 0; j < 4; ++j) {
    float v = acc[j] * inv;
    v = v > 0.f ? v : expm1f(v);
    ov[j] = f2bf(v);
  }
  *reinterpret_cast<u16x4*>(h1b + (size_t)n * 256 + t * 4) = ov;
}

// ---------------- GraphConv aggregation: one wave/node ----------------
__global__ __launch_bounds__(64) void agg_gc(const ushort* __restrict__ Sb,
                                             const int* __restrict__ rp,
                                             const int* __restrict__ scol,
                                             const float* __restrict__ b_gc,
                                             ushort* __restrict__ h2b, int N) {
  int n = blockIdx.x;
  int t = threadIdx.x;
  float acc[4] = {0.f, 0.f, 0.f, 0.f};
  int beg = rp[n], end = rp[n + 1];
  for (int i = beg; i < end; ++i) {
    int c = scol[i];
    const u16x4 sv = *reinterpret_cast<const u16x4*>(Sb + (size_t)c * 256 + t * 4);
#pragma unroll
    for (int j = 0; j < 4; ++j) acc[j] += bf2f(sv[j]);
  }
  const float4 bv = *reinterpret_cast<const float4*>(b_gc + t * 4);
  float o[4] = {acc[0] + bv.x, acc[1] + bv.y, acc[2] + bv.z, acc[3] + bv.w};
  u16x4 ov;
#pragma unroll
  for (int j = 0; j < 4; ++j) ov[j] = f2bf(o[j]);
  *reinterpret_cast<u16x4*>(h2b + (size_t)n * 256 + t * 4) = ov;
}

// ---------------- output head aggregation + elu + log_softmax ----------------
__global__ __launch_bounds__(64) void agg_out_lsm(const ushort* __restrict__ Hob,
                                                  const float* __restrict__ wo,
                                                  const int* __restrict__ rp,
                                                  const int* __restrict__ scol,
                                                  float* __restrict__ out0, int N) {
  int n = blockIdx.x;
  int t = threadIdx.x;
  float acc = 0.f, rs = 0.f;
  int beg = rp[n], end = rp[n + 1];
  for (int i = beg; i < end; ++i) {
    int c = scol[i];
    float wv = wo[i];
    rs += wv;
    if (t < 40) acc = fmaf(wv, bf2f(Hob[(size_t)c * 40 + t]), acc);
  }
  float hp = acc / (rs + 1e-16f);
  float xo = (t < 40) ? (hp > 0.f ? hp : expm1f(hp)) : -3.0e38f;
  float mx = xo;
#pragma unroll
  for (int m = 1; m < 64; m <<= 1) mx = fmaxf(mx, __shfl_xor(mx, m));
  float ex = (t < 40) ? expf(xo - mx) : 0.f;
  float sum = ex;
#pragma unroll
  for (int m = 1; m < 64; m <<= 1) sum += __shfl_xor(sum, m);
  if (t < 40) out0[(size_t)n * 40 + t] = xo - mx - logf(sum);
}

// ---------------- launch ----------------
extern "C" void kernel_launch(void* const* d_in, const int* in_sizes, int n_in,
                              void* d_out, int out_size, void* d_ws, size_t ws_size,
                              hipStream_t stream) {
  const float* x      = (const float*)d_in[0];
  const int*   ei     = (const int*)d_in[1];
  const float* W_att  = (const float*)d_in[2];
  const float* a1     = (const float*)d_in[3];
  const float* a2     = (const float*)d_in[4];
  const float* W_out  = (const float*)d_in[5];
  const float* a1_out = (const float*)d_in[6];
  const float* a2_out = (const float*)d_in[7];
  const float* W_gc   = (const float*)d_in[8];
  const float* b_gc   = (const float*)d_in[9];
  const float* W_enc  = (const float*)d_in[10];
  const float* b_enc  = (const float*)d_in[11];

  const int N = in_sizes[0] / 256;
  const int E = in_sizes[1] / 2;
  const int N64 = (N + 63) & ~63;   // padded row count
  const int* row = ei;
  const int* col = ei + E;

  char* p = (char*)d_ws;
  auto alloc = [&](size_t bytes) -> void* {
    void* r = (void*)p;
    p += (bytes + 255) & ~(size_t)255;
    return r;
  };
  ushort* hbuf = (ushort*)alloc((size_t)N64 * 256 * 2);      // bf16: H, then support
  ushort* h1b  = (ushort*)alloc((size_t)2 * N64 * 256 * 2);  // h1b ‖ h2b (padded halves)
  ushort* h2b  = h1b + (size_t)N64 * 256;
  float* Ho   = (float*)alloc((size_t)N * 40 * 4);
  ushort* Hob = (ushort*)alloc((size_t)N * 40 * 2);
  float* s1   = (float*)alloc((size_t)N * 8 * 4);
  float* s2   = (float*)alloc((size_t)N * 8 * 4);
  float* s1o  = (float*)alloc((size_t)N * 4);
  float* s2o  = (float*)alloc((size_t)N * 4);
  int* deg    = (int*)alloc((size_t)2 * N * 4);  // deg ‖ cursor (one memset)
  int* cur    = deg + N;
  int* rp     = (int*)alloc((size_t)(N + 1) * 4);
  int* bsum   = (int*)alloc(256 * 4);
  int* scol   = (int*)alloc((size_t)E * 4);
  int* srow   = (int*)alloc((size_t)E * 4);
  float* wo   = (float*)alloc((size_t)E * 4);
  ushort* Bp  = (ushort*)alloc((size_t)65536 * 2);
  ushort* Wg  = (ushort*)alloc((size_t)65536 * 2);
  ushort* We  = (ushort*)alloc((size_t)32768 * 2);
  ushort* Wo  = (ushort*)alloc((size_t)16384 * 2);

  float* out0 = (float*)d_out;
  float* outY = out0 + (size_t)N * 40;   // outZ follows contiguously (N*128 later)

  const int nb = (N + 255) / 256;
  const int gblk = N64 / 64;
  const int gblk2 = 2 * N64 / 64;

  // fused weight packing
  pack_all<<<dim3((180224 + 255) / 256), dim3(256), 0, stream>>>(
      W_att, W_gc, W_enc, W_out, Bp, Wg, We, Wo);

  // CSR build (counting sort by row); deg+cur zeroed in one memset
  hipMemsetAsync(deg, 0, (size_t)2 * N * 4, stream);
  hist_deg<<<dim3((E + 255) / 256), dim3(256), 0, stream>>>(row, deg, E);
  scan1<<<dim3(nb), dim3(256), 0, stream>>>(deg, rp, bsum, N);
  scan2<<<dim3(1), dim3(256), 0, stream>>>(bsum, nb);
  scan3<<<dim3(nb), dim3(256), 0, stream>>>(rp, bsum, N, E);
  scatter_edges<<<dim3((E + 255) / 256), dim3(256), 0, stream>>>(row, col, rp, cur, scol, srow, E);

  // layer 1: H = x @ W_att(all heads), bf16 out
  gemm_mfma<256, 256, 2, false, false><<<dim3(gblk), dim3(512), 0, stream>>>(
      x, nullptr, Bp, nullptr, nullptr, hbuf, N, 0);
  calc_s12<<<dim3((N * 8 + 255) / 256), dim3(256), 0, stream>>>(hbuf, a1, a2, s1, s2, N);
  agg_att<<<dim3(N), dim3(64), 0, stream>>>(hbuf, s1, s2, rp, scol, h1b, N);

  // GraphConv: support bf16 (overwrites hbuf)
  gemm_mfma<256, 256, 2, false, true><<<dim3(gblk), dim3(512), 0, stream>>>(
      nullptr, h1b, Wg, nullptr, nullptr, hbuf, N, 0);
  agg_gc<<<dim3(N), dim3(64), 0, stream>>>(hbuf, rp, scol, b_gc, h2b, N);

  // output head: Ho f32 (for s12o) + bf16 copy (for gather)
  gemm_mfma<64, 40, 1, false, true><<<dim3(gblk), dim3(512), 0, stream>>>(
      nullptr, h2b, Wo, nullptr, Ho, Hob, N, 0);
  calc_s12_out<<<dim3((N + 255) / 256), dim3(256), 0, stream>>>(Ho, a1_out, a2_out, s1o, s2o, N);
  edge_wo<<<dim3((E + 255) / 256), dim3(256), 0, stream>>>(srow, scol, s1o, s2o, wo, E);
  agg_out_lsm<<<dim3(N), dim3(64), 0, stream>>>(Hob, wo, rp, scol, out0, N);

  // y ‖ z in one GEMM over padded halves: y rows [0,N), z rows [N64,N64+N)
  gemm_mfma<128, 128, 0, true, true><<<dim3(gblk2), dim3(512), 0, stream>>>(
      nullptr, h1b, We, b_enc, outY, nullptr, N, N64);
}

// Round 16
// 389.388 us; speedup vs baseline: 1.2501x; 1.0326x over previous
//
#include <hip/hip_runtime.h>
#include <math.h>

// N=50000, E=800000, nfeat=256, hid=256, nclass=40, nstruc=128, heads=8
typedef __attribute__((ext_vector_type(8))) short short8;
typedef __attribute__((ext_vector_type(4))) ushort u16x4;
typedef __attribute__((ext_vector_type(8))) ushort u16x8;
typedef __attribute__((ext_vector_type(8))) __bf16 bf16x8;
typedef __attribute__((ext_vector_type(4))) float f32x4;

#define LOG2E 1.44269504088896f

__device__ inline ushort f2bf(float x) {
  union { float f; unsigned u; } v; v.f = x;
  unsigned r = v.u + 0x7fff + ((v.u >> 16) & 1);
  return (ushort)(r >> 16);
}
__device__ inline float bf2f(ushort b) {
  union { unsigned u; float f; } v; v.u = (unsigned)b << 16; return v.f;
}

#define GLOAD_LDS16(g, l)                                                      \
  __builtin_amdgcn_global_load_lds(                                            \
      (const __attribute__((address_space(1))) void*)(g),                      \
      (__attribute__((address_space(3))) void*)(l), 16, 0, 0)

// ---------------- fused weight packing (all 4 weights + s-matvecs, one launch) ----------------
__device__ inline void pack_one(float val, int k, int n, int Fp, ushort* __restrict__ dst) {
  int kb = k >> 5, kr = k & 31;
  int lane = ((kr >> 3) << 4) | (n & 15);
  int j = kr & 7;
  int nb = n >> 4;
  size_t off = ((size_t)(kb * (Fp / 16) + nb) * 64 + lane) * 8 + j;
  dst[off] = f2bf(val);
}

__global__ void pack_all(const float* __restrict__ W_att, const float* __restrict__ W_gc,
                         const float* __restrict__ W_enc, const float* __restrict__ W_out,
                         const float* __restrict__ a1o, const float* __restrict__ a2o,
                         ushort* __restrict__ Bp, ushort* __restrict__ Wg,
                         ushort* __restrict__ We, ushort* __restrict__ Wo) {
  int tid = blockIdx.x * blockDim.x + threadIdx.x;
  if (tid < 65536) {
    int k = tid >> 8, n = tid & 255;
    float val = W_att[(size_t)(n >> 5) * 8192 + k * 32 + (n & 31)];
    pack_one(val, k, n, 256, Bp);
  } else if (tid < 131072) {
    int t2 = tid - 65536;
    int k = t2 >> 8, n = t2 & 255;
    pack_one(W_gc[k * 256 + n], k, n, 256, Wg);
  } else if (tid < 163840) {
    int t2 = tid - 131072;
    int k = t2 >> 7, n = t2 & 127;
    pack_one(W_enc[k * 128 + n], k, n, 128, We);
  } else if (tid < 180224) {
    int t2 = tid - 163840;
    int k = t2 >> 6, n = t2 & 63;
    float val;
    if (n < 40) {
      val = W_out[k * 40 + n];
    } else if (n == 40) {          // col 40: W_out @ a1_out
      val = 0.f;
      for (int j = 0; j < 40; ++j) val = fmaf(W_out[k * 40 + j], a1o[j], val);
    } else if (n == 41) {          // col 41: W_out @ a2_out
      val = 0.f;
      for (int j = 0; j < 40; ++j) val = fmaf(W_out[k * 40 + j], a2o[j], val);
    } else {
      val = 0.f;
    }
    pack_one(val, k, n, 64, Wo);
  }
}

// ---------------- bf16 MFMA GEMM: C = A[.,256] @ B[256,F] (+bias) ----------------
// BM=64, 512 threads (8 waves: 2 row x 4 col groups), 2 row-frags/wave, 32 KiB LDS.
// BFIN: bf16 input staged via global_load_lds (linear LDS dest, pre-swizzled source).
// NPAD>0: merged-yz row remap. SOUT: cols 40/41 -> s1o/s2o (f32).
template <int Fp, int F, int OUTMODE, bool BIAS, bool BFIN, bool SOUT>
__global__ __launch_bounds__(512) void gemm_mfma(const float* __restrict__ A,
                                                 const ushort* __restrict__ Ab,
                                                 const ushort* __restrict__ Bp,
                                                 const float* __restrict__ bias,
                                                 float* __restrict__ C,
                                                 ushort* __restrict__ Cb,
                                                 float* __restrict__ s1o,
                                                 float* __restrict__ s2o, int Nv, int NPAD) {
  constexpr int NB = Fp / 64;
  __shared__ ushort lhs[64 * 256];
  int n0 = blockIdx.x * 64;
  int t = threadIdx.x;
  int wv = t >> 6, l = t & 63;
  if (BFIN) {
#pragma unroll
    for (int i = 0; i < 4; ++i) {
      int u = i * 512 + wv * 64 + l;
      int r = u >> 5, cs = u & 31;
      int csrc = cs ^ (r & 7);
      const ushort* src = Ab + (size_t)(n0 + r) * 256 + csrc * 8;
      GLOAD_LDS16(src, lhs + (size_t)(i * 512 + wv * 64) * 8);
    }
  } else {
    int r = t >> 3, q = t & 7;
    int row = n0 + r;
    bool rin = row < Nv;
#pragma unroll
    for (int i = 0; i < 4; ++i) {
      int c0 = q * 32 + i * 8;
      int c8 = (c0 >> 3) ^ (r & 7);
      float4 f0 = {0.f, 0.f, 0.f, 0.f}, f1 = {0.f, 0.f, 0.f, 0.f};
      if (rin) {
        f0 = *reinterpret_cast<const float4*>(A + (size_t)row * 256 + c0);
        f1 = *reinterpret_cast<const float4*>(A + (size_t)row * 256 + c0 + 4);
      }
      float ff[8] = {f0.x, f0.y, f0.z, f0.w, f1.x, f1.y, f1.z, f1.w};
      short8 sh;
#pragma unroll
      for (int j = 0; j < 8; ++j) sh[j] = (short)f2bf(ff[j]);
      *reinterpret_cast<short8*>(&lhs[r * 256 + c8 * 8]) = sh;
    }
  }
  __syncthreads();
  int wr = wv >> 2, wc = wv & 3;
  int lr = l & 15, lk = l >> 4;
  f32x4 acc[2][NB];
#pragma unroll
  for (int m = 0; m < 2; ++m)
#pragma unroll
    for (int nb = 0; nb < NB; ++nb) acc[m][nb] = (f32x4){0.f, 0.f, 0.f, 0.f};

#pragma unroll
  for (int ks = 0; ks < 8; ++ks) {
    bf16x8 ah[2];
#pragma unroll
    for (int m = 0; m < 2; ++m) {
      int row = wr * 32 + m * 16 + lr;
      int c8 = (ks * 4 + lk) ^ (row & 7);
      ah[m] = *reinterpret_cast<const bf16x8*>(&lhs[row * 256 + c8 * 8]);
    }
#pragma unroll
    for (int nb = 0; nb < NB; ++nb) {
      size_t off = ((size_t)(ks * (Fp / 16) + wc * NB + nb) * 64 + l) * 8;
      bf16x8 bh = *reinterpret_cast<const bf16x8*>(&Bp[off]);
#pragma unroll
      for (int m = 0; m < 2; ++m)
        acc[m][nb] = __builtin_amdgcn_mfma_f32_16x16x32_bf16(ah[m], bh, acc[m][nb], 0, 0, 0);
    }
  }
#pragma unroll
  for (int m = 0; m < 2; ++m) {
    int rowbase = n0 + wr * 32 + m * 16 + lk * 4;
#pragma unroll
    for (int nb = 0; nb < NB; ++nb) {
      int col = wc * (NB * 16) + nb * 16 + lr;
#pragma unroll
      for (int rg = 0; rg < 4; ++rg) {
        int gr = rowbase + rg;
        int crow;
        bool ok;
        if (NPAD == 0) {
          crow = gr; ok = gr < Nv;
        } else if (gr < NPAD) {
          crow = gr; ok = gr < Nv;
        } else {
          int g2 = gr - NPAD;
          crow = Nv + g2; ok = g2 < Nv;
        }
        if (ok) {
          float v = acc[m][nb][rg];
          if (col < F) {
            if (BIAS) v += bias[col];
            if (OUTMODE != 2) C[(size_t)crow * F + col] = v;
            if (OUTMODE != 0) Cb[(size_t)crow * F + col] = f2bf(v);
          } else if (SOUT && col == 40) {
            s1o[crow] = v;
          } else if (SOUT && col == 41) {
            s2o[crow] = v;
          }
        }
      }
    }
  }
}

// ---------------- s1/s2 per node per head (bf16 H input) ----------------
__global__ void calc_s12(const ushort* __restrict__ Hb, const float* __restrict__ a1,
                         const float* __restrict__ a2, float* __restrict__ s1,
                         float* __restrict__ s2, int N) {
  int tid = blockIdx.x * blockDim.x + threadIdx.x;
  if (tid >= N * 8) return;
  int h = tid & 7;
  int n = tid >> 3;
  const ushort* hp = Hb + (size_t)n * 256 + h * 32;
  const float* A1 = a1 + h * 32;
  const float* A2 = a2 + h * 32;
  float d1 = 0.f, d2 = 0.f;
#pragma unroll
  for (int j0 = 0; j0 < 32; j0 += 8) {
    u16x8 hv = *reinterpret_cast<const u16x8*>(hp + j0);
#pragma unroll
    for (int j = 0; j < 8; ++j) {
      float v = bf2f(hv[j]);
      d1 = fmaf(v, A1[j0 + j], d1);
      d2 = fmaf(v, A2[j0 + j], d2);
    }
  }
  s1[tid] = d1;
  s2[tid] = d2;
}

// ---------------- CSR build ----------------
__global__ void hist_deg(const int* __restrict__ row, int* __restrict__ deg, int E) {
  int e = blockIdx.x * blockDim.x + threadIdx.x;
  if (e < E) atomicAdd(&deg[row[e]], 1);
}

__global__ void scan1(const int* __restrict__ deg, int* __restrict__ rp, int* __restrict__ bsum,
                      int N) {
  __shared__ int sd[256];
  int t = threadIdx.x;
  int i = blockIdx.x * 256 + t;
  int v = (i < N) ? deg[i] : 0;
  sd[t] = v;
  __syncthreads();
  for (int off = 1; off < 256; off <<= 1) {
    int x = (t >= off) ? sd[t - off] : 0;
    __syncthreads();
    sd[t] += x;
    __syncthreads();
  }
  if (i < N) rp[i] = sd[t] - v;
  if (t == 255) bsum[blockIdx.x] = sd[255];
}

__global__ void scan2(int* __restrict__ bsum, int nb) {
  __shared__ int sd[256];
  int t = threadIdx.x;
  int v = (t < nb) ? bsum[t] : 0;
  sd[t] = v;
  __syncthreads();
  for (int off = 1; off < 256; off <<= 1) {
    int x = (t >= off) ? sd[t - off] : 0;
    __syncthreads();
    sd[t] += x;
    __syncthreads();
  }
  if (t < nb) bsum[t] = sd[t] - v;
}

__global__ void scan3(int* __restrict__ rp, const int* __restrict__ bsum, int N, int E) {
  int i = blockIdx.x * 256 + threadIdx.x;
  if (i < N) rp[i] += bsum[blockIdx.x];
  if (i == 0) rp[N] = E;
}

__global__ void scatter_edges(const int* __restrict__ row, const int* __restrict__ col,
                              const int* __restrict__ rp, int* __restrict__ cur,
                              int* __restrict__ scol, int* __restrict__ srow, int E) {
  int e = blockIdx.x * blockDim.x + threadIdx.x;
  if (e >= E) return;
  int r = row[e];
  int p = atomicAdd(&cur[r], 1);
  int idx = rp[r] + p;
  scol[idx] = col[e];
  srow[idx] = r;
}

// ---------------- output-head edge weights (parallel, hw exp) ----------------
__global__ void edge_wo(const int* __restrict__ srow, const int* __restrict__ scol,
                        const float* __restrict__ s1o, const float* __restrict__ s2o,
                        float* __restrict__ wo, int E) {
  int e = blockIdx.x * blockDim.x + threadIdx.x;
  if (e >= E) return;
  float lg = s1o[srow[e]] + s2o[scol[e]];
  float lr = lg > 0.f ? lg : 0.2f * lg;
  wo[e] = __builtin_amdgcn_exp2f(-LOG2E * lr);
}

// ---------------- GAT layer-1 aggregation (fused hw-exp weights): one wave/node ----------------
__global__ __launch_bounds__(64) void agg_att(const ushort* __restrict__ Hb,
                                              const float* __restrict__ s1,
                                              const float* __restrict__ s2,
                                              const int* __restrict__ rp,
                                              const int* __restrict__ scol,
                                              ushort* __restrict__ h1b, int N) {
  int n = blockIdx.x;
  int t = threadIdx.x;          // features t*4..t*4+3 ; head = t>>3
  int head = t >> 3;
  float s1n = s1[n * 8 + head];
  float acc[4] = {0.f, 0.f, 0.f, 0.f};
  float rs = 0.f;
  int beg = rp[n], end = rp[n + 1];
  for (int i = beg; i < end; ++i) {
    int c = scol[i];
    float lg = s1n + s2[c * 8 + head];
    float lr = lg > 0.f ? lg : 0.2f * lg;
    float wv = __builtin_amdgcn_exp2f(-LOG2E * lr);
    rs += wv;
    const u16x4 hv = *reinterpret_cast<const u16x4*>(Hb + (size_t)c * 256 + t * 4);
#pragma unroll
    for (int j = 0; j < 4; ++j) acc[j] = fmaf(wv, bf2f(hv[j]), acc[j]);
  }
  float inv = 1.f / (rs + 1e-16f);
  u16x4 ov;
#pragma unroll
  for (int j = 0; j < 4; ++j) {
    float v = acc[j] * inv;
    v = v > 0.f ? v : expm1f(v);
    ov[j] = f2bf(v);
  }
  *reinterpret_cast<u16x4*>(h1b + (size_t)n * 256 + t * 4) = ov;
}

// ---------------- GraphConv aggregation: one wave/node ----------------
__global__ __launch_bounds__(64) void agg_gc(const ushort* __restrict__ Sb,
                                             const int* __restrict__ rp,
                                             const int* __restrict__ scol,
                                             const float* __restrict__ b_gc,
                                             ushort* __restrict__ h2b, int N) {
  int n = blockIdx.x;
  int t = threadIdx.x;
  float acc[4] = {0.f, 0.f, 0.f, 0.f};
  int beg = rp[n], end = rp[n + 1];
  for (int i = beg; i < end; ++i) {
    int c = scol[i];
    const u16x4 sv = *reinterpret_cast<const u16x4*>(Sb + (size_t)c * 256 + t * 4);
#pragma unroll
    for (int j = 0; j < 4; ++j) acc[j] += bf2f(sv[j]);
  }
  const float4 bv = *reinterpret_cast<const float4*>(b_gc + t * 4);
  float o[4] = {acc[0] + bv.x, acc[1] + bv.y, acc[2] + bv.z, acc[3] + bv.w};
  u16x4 ov;
#pragma unroll
  for (int j = 0; j < 4; ++j) ov[j] = f2bf(o[j]);
  *reinterpret_cast<u16x4*>(h2b + (size_t)n * 256 + t * 4) = ov;
}

// ---------------- output head aggregation + elu + log_softmax ----------------
__global__ __launch_bounds__(64) void agg_out_lsm(const ushort* __restrict__ Hob,
                                                  const float* __restrict__ wo,
                                                  const int* __restrict__ rp,
                                                  const int* __restrict__ scol,
                                                  float* __restrict__ out0, int N) {
  int n = blockIdx.x;
  int t = threadIdx.x;
  float acc = 0.f, rs = 0.f;
  int beg = rp[n], end = rp[n + 1];
  for (int i = beg; i < end; ++i) {
    int c = scol[i];
    float wv = wo[i];
    rs += wv;
    if (t < 40) acc = fmaf(wv, bf2f(Hob[(size_t)c * 40 + t]), acc);
  }
  float hp = acc / (rs + 1e-16f);
  float xo = (t < 40) ? (hp > 0.f ? hp : expm1f(hp)) : -3.0e38f;
  float mx = xo;
#pragma unroll
  for (int m = 1; m < 64; m <<= 1) mx = fmaxf(mx, __shfl_xor(mx, m));
  float ex = (t < 40) ? expf(xo - mx) : 0.f;
  float sum = ex;
#pragma unroll
  for (int m = 1; m < 64; m <<= 1) sum += __shfl_xor(sum, m);
  if (t < 40) out0[(size_t)n * 40 + t] = xo - mx - logf(sum);
}

// ---------------- launch ----------------
extern "C" void kernel_launch(void* const* d_in, const int* in_sizes, int n_in,
                              void* d_out, int out_size, void* d_ws, size_t ws_size,
                              hipStream_t stream) {
  const float* x      = (const float*)d_in[0];
  const int*   ei     = (const int*)d_in[1];
  const float* W_att  = (const float*)d_in[2];
  const float* a1     = (const float*)d_in[3];
  const float* a2     = (const float*)d_in[4];
  const float* W_out  = (const float*)d_in[5];
  const float* a1_out = (const float*)d_in[6];
  const float* a2_out = (const float*)d_in[7];
  const float* W_gc   = (const float*)d_in[8];
  const float* b_gc   = (const float*)d_in[9];
  const float* W_enc  = (const float*)d_in[10];
  const float* b_enc  = (const float*)d_in[11];

  const int N = in_sizes[0] / 256;
  const int E = in_sizes[1] / 2;
  const int N64 = (N + 63) & ~63;
  const int* row = ei;
  const int* col = ei + E;

  char* p = (char*)d_ws;
  auto alloc = [&](size_t bytes) -> void* {
    void* r = (void*)p;
    p += (bytes + 255) & ~(size_t)255;
    return r;
  };
  ushort* hbuf = (ushort*)alloc((size_t)N64 * 256 * 2);
  ushort* h1b  = (ushort*)alloc((size_t)2 * N64 * 256 * 2);
  ushort* h2b  = h1b + (size_t)N64 * 256;
  ushort* Hob = (ushort*)alloc((size_t)N * 40 * 2);
  float* s1   = (float*)alloc((size_t)N * 8 * 4);
  float* s2   = (float*)alloc((size_t)N * 8 * 4);
  float* s1o  = (float*)alloc((size_t)N * 4);
  float* s2o  = (float*)alloc((size_t)N * 4);
  int* deg    = (int*)alloc((size_t)2 * N * 4);
  int* cur    = deg + N;
  int* rp     = (int*)alloc((size_t)(N + 1) * 4);
  int* bsum   = (int*)alloc(256 * 4);
  int* scol   = (int*)alloc((size_t)E * 4);
  int* srow   = (int*)alloc((size_t)E * 4);
  float* wo   = (float*)alloc((size_t)E * 4);
  ushort* Bp  = (ushort*)alloc((size_t)65536 * 2);
  ushort* Wg  = (ushort*)alloc((size_t)65536 * 2);
  ushort* We  = (ushort*)alloc((size_t)32768 * 2);
  ushort* Wo  = (ushort*)alloc((size_t)16384 * 2);

  float* out0 = (float*)d_out;
  float* outY = out0 + (size_t)N * 40;

  const int nb = (N + 255) / 256;
  const int gblk = N64 / 64;
  const int gblk2 = 2 * N64 / 64;

  // fused weight packing (+ s1o/s2o matvec columns)
  pack_all<<<dim3((180224 + 255) / 256), dim3(256), 0, stream>>>(
      W_att, W_gc, W_enc, W_out, a1_out, a2_out, Bp, Wg, We, Wo);

  // CSR build
  hipMemsetAsync(deg, 0, (size_t)2 * N * 4, stream);
  hist_deg<<<dim3((E + 255) / 256), dim3(256), 0, stream>>>(row, deg, E);
  scan1<<<dim3(nb), dim3(256), 0, stream>>>(deg, rp, bsum, N);
  scan2<<<dim3(1), dim3(256), 0, stream>>>(bsum, nb);
  scan3<<<dim3(nb), dim3(256), 0, stream>>>(rp, bsum, N, E);
  scatter_edges<<<dim3((E + 255) / 256), dim3(256), 0, stream>>>(row, col, rp, cur, scol, srow, E);

  // layer 1: H = x @ W_att(all heads), bf16 out
  gemm_mfma<256, 256, 2, false, false, false><<<dim3(gblk), dim3(512), 0, stream>>>(
      x, nullptr, Bp, nullptr, nullptr, hbuf, nullptr, nullptr, N, 0);
  calc_s12<<<dim3((N * 8 + 255) / 256), dim3(256), 0, stream>>>(hbuf, a1, a2, s1, s2, N);
  agg_att<<<dim3(N), dim3(64), 0, stream>>>(hbuf, s1, s2, rp, scol, h1b, N);

  // GraphConv: support bf16 (overwrites hbuf)
  gemm_mfma<256, 256, 2, false, true, false><<<dim3(gblk), dim3(512), 0, stream>>>(
      nullptr, h1b, Wg, nullptr, nullptr, hbuf, nullptr, nullptr, N, 0);
  agg_gc<<<dim3(N), dim3(64), 0, stream>>>(hbuf, rp, scol, b_gc, h2b, N);

  // output head: Hob bf16 + fused s1o/s2o (cols 40/41)
  gemm_mfma<64, 40, 2, false, true, true><<<dim3(gblk), dim3(512), 0, stream>>>(
      nullptr, h2b, Wo, nullptr, nullptr, Hob, s1o, s2o, N, 0);
  edge_wo<<<dim3((E + 255) / 256), dim3(256), 0, stream>>>(srow, scol, s1o, s2o, wo, E);
  agg_out_lsm<<<dim3(N), dim3(64), 0, stream>>>(Hob, wo, rp, scol, out0, N);

  // y ‖ z in one GEMM over padded halves
  gemm_mfma<128, 128, 0, true, true, false><<<dim3(gblk2), dim3(512), 0, stream>>>(
      nullptr, h1b, We, b_enc, outY, nullptr, nullptr, nullptr, N, N64);
}